// Round 1
// baseline (728.615 us; speedup 1.0000x reference)
//
#include <hip/hip_runtime.h>

typedef unsigned short UST;
typedef __bf16 bf16x8 __attribute__((ext_vector_type(8)));
typedef float floatx4 __attribute__((ext_vector_type(4)));
typedef unsigned short ushort8v __attribute__((ext_vector_type(8)));
typedef unsigned short ushort4v __attribute__((ext_vector_type(4)));

#define N_NODES 20000
#define E_EDGES 320000
#define KE 928         // padded edge-MLP K: [hi 0:256 | hj 256:512 | fd 512:896 | le 896:905 | 0 pad:928]
#define M_PAD 20096    // 157*128

static __device__ __forceinline__ UST f2bf(float x){
  unsigned int u = __float_as_uint(x);
  u += 0x7fffu + ((u >> 16) & 1u);   // round-to-nearest-even
  return (UST)(u >> 16);
}
static __device__ __forceinline__ float siluf(float v){
  return v / (1.0f + __expf(-v));
}
// async global->LDS, 16B per lane; LDS dest must be wave-uniform-base + lane*16
static __device__ __forceinline__ void gll16(const void* g, void* lds){
  __builtin_amdgcn_global_load_lds(
      (const __attribute__((address_space(1))) unsigned int*)g,
      (__attribute__((address_space(3))) unsigned int*)lds, 16, 0, 0);
}

static __device__ __forceinline__ void mfma_step(const UST* As, const UST* Bs,
    floatx4 (&acc)[4][4], int lm, int quad, int wM, int wN){
  bf16x8 a[4], b[4];
#pragma unroll
  for (int i = 0; i < 4; ++i)
    a[i] = *(const bf16x8*)(As + (wM + i*16 + lm)*32 + quad*8);
#pragma unroll
  for (int i = 0; i < 4; ++i)
    b[i] = *(const bf16x8*)(Bs + (wN + i*16 + lm)*32 + quad*8);
#pragma unroll
  for (int mi = 0; mi < 4; ++mi)
#pragma unroll
    for (int ni = 0; ni < 4; ++ni)
      acc[mi][ni] = __builtin_amdgcn_mfma_f32_16x16x32_bf16(a[mi], b[ni], acc[mi][ni], 0, 0, 0);
}

// ---------------- LayerNorm: one wave per row, h -> bf16 ----------------
__global__ __launch_bounds__(256) void ln_kernel(const float* __restrict__ x,
    const float* __restrict__ gamma, const float* __restrict__ beta,
    UST* __restrict__ h){
  int wave = threadIdx.x >> 6, lane = threadIdx.x & 63;
  int row = blockIdx.x * 4 + wave;
  const float4* xp = (const float4*)(x + (size_t)row * 256);
  float4 v = xp[lane];
  float s  = v.x + v.y + v.z + v.w;
  float sq = v.x*v.x + v.y*v.y + v.z*v.z + v.w*v.w;
#pragma unroll
  for (int o = 32; o > 0; o >>= 1){ s += __shfl_xor(s, o); sq += __shfl_xor(sq, o); }
  float mu  = s * (1.0f/256.0f);
  float var = sq * (1.0f/256.0f) - mu*mu;
  float rs  = rsqrtf(var + 1e-5f);
  float4 g = ((const float4*)gamma)[lane];
  float4 b = ((const float4*)beta)[lane];
  ushort4v o4;
  o4[0] = f2bf((v.x-mu)*rs*g.x + b.x);
  o4[1] = f2bf((v.y-mu)*rs*g.y + b.y);
  o4[2] = f2bf((v.z-mu)*rs*g.z + b.z);
  o4[3] = f2bf((v.w-mu)*rs*g.w + b.w);
  *(ushort4v*)(h + (size_t)row*256 + lane*4) = o4;
}

// ---------------- ltl = L @ L^T per graph ----------------
__global__ __launch_bounds__(256) void ltl_kernel(const float* __restrict__ lat,
                                                  float* __restrict__ ltl){
  int i = blockIdx.x*256 + threadIdx.x;
  if (i >= 9000) return;
  int g = i / 9, ij = i % 9, a = ij / 3, b = ij % 3;
  const float* L = lat + g*9;
  ltl[i] = L[a*3+0]*L[b*3+0] + L[a*3+1]*L[b*3+1] + L[a*3+2]*L[b*3+2];
}

// ---------------- weight prep: transpose -> bf16 (We1 rows permuted) ----------------
__global__ __launch_bounds__(256) void prep_w(const float* __restrict__ We1,
    const float* __restrict__ We2, const float* __restrict__ Wn1,
    const float* __restrict__ Wn2, UST* __restrict__ W1T, UST* __restrict__ W2T,
    UST* __restrict__ Wn1T, UST* __restrict__ Wn2T){
  int i = blockIdx.x*256 + threadIdx.x;
  if (i < 256*KE){
    int n = i / KE, k = i % KE;
    float v = 0.0f;
    if (k < 512)      v = We1[(size_t)k*256 + n];          // hi|hj
    else if (k < 896) v = We1[(size_t)(k+9)*256 + n];      // fd (orig rows 521..904)
    else if (k < 905) v = We1[(size_t)(k-384)*256 + n];    // le (orig rows 512..520)
    W1T[i] = f2bf(v);
  }
  if (i < 256*256){
    int n = i >> 8, k = i & 255;
    W2T[i]  = f2bf(We2[(size_t)k*256 + n]);
    Wn2T[i] = f2bf(Wn2[(size_t)k*256 + n]);
  }
  if (i < 256*512){
    int n = i >> 9, k = i & 511;
    Wn1T[i] = f2bf(Wn1[(size_t)k*256 + n]);
  }
}

// ---------------- edge counts ----------------
__global__ __launch_bounds__(256) void cnt_kernel(const int* __restrict__ src,
                                                  float* __restrict__ cnt){
  int e = blockIdx.x*256 + threadIdx.x;
  if (e < E_EDGES) atomicAdd(&cnt[src[e]], 1.0f);
}

// ---------------- GEMM1: fused x-construction, e1 = silu(x @ We1 + be1) ----------------
__global__ __launch_bounds__(256)
void gemm_edge1(const UST* __restrict__ h, const int* __restrict__ ei,
                const int* __restrict__ e2g, const float* __restrict__ fdif,
                const float* __restrict__ ltl, const UST* __restrict__ W1T,
                const float* __restrict__ be1, UST* __restrict__ e1){
  __shared__ __attribute__((aligned(16))) UST As[128*32];
  __shared__ __attribute__((aligned(16))) UST Bs[128*32];
  int t = threadIdx.x;
  int bM = blockIdx.x, bN = blockIdx.y;
  int rA = t >> 2, cA = (t & 3) * 8;
  int r0 = bM*128 + rA, r1 = r0 + 64;
  int src0 = ei[r0], src1 = ei[r1];
  int dst0 = ei[E_EDGES + r0], dst1 = ei[E_EDGES + r1];
  int g0 = e2g[r0], g1 = e2g[r1];
  float f0x = fdif[r0*3+0], f0y = fdif[r0*3+1], f0z = fdif[r0*3+2];
  float f1x = fdif[r1*3+0], f1y = fdif[r1*3+1], f1z = fdif[r1*3+2];
  size_t btb0 = (size_t)(bN*128 + rA)*KE + cA;
  size_t btb1 = btb0 + (size_t)64*KE;
  int lane = t & 63, lm = lane & 15, quad = lane >> 4;
  int wave = t >> 6, wM = (wave >> 1)*64, wN = (wave & 1)*64;
  floatx4 acc[4][4] = {};
  UST* a_d0 = &As[rA*32 + cA];
  UST* a_d1 = &As[(64+rA)*32 + cA];
  UST* b_d0 = &Bs[rA*32 + cA];
  UST* b_d1 = &Bs[(64+rA)*32 + cA];

  int step = 0;
#pragma unroll 1
  for (; step < 8; ++step){            // hi: gather h[src]
    int k0 = step*32;
    gll16(h + (size_t)src0*256 + k0 + cA, a_d0);
    gll16(h + (size_t)src1*256 + k0 + cA, a_d1);
    gll16(W1T + btb0 + k0, b_d0);
    gll16(W1T + btb1 + k0, b_d1);
    __syncthreads();
    mfma_step(As, Bs, acc, lm, quad, wM, wN);
    __syncthreads();
  }
#pragma unroll 1
  for (; step < 16; ++step){           // hj: gather h[dst]
    int k0 = step*32;
    int kk = k0 - 256 + cA;
    gll16(h + (size_t)dst0*256 + kk, a_d0);
    gll16(h + (size_t)dst1*256 + kk, a_d1);
    gll16(W1T + btb0 + k0, b_d0);
    gll16(W1T + btb1 + k0, b_d1);
    __syncthreads();
    mfma_step(As, Bs, acc, lm, quad, wM, wN);
    __syncthreads();
  }
#pragma unroll 1
  for (; step < 28; ++step){           // fd: sin/cos(2*pi*frac*k)
    int k0 = step*32;
    int j0 = k0 - 512 + cA;
    bool issin = j0 < 192;
    int jj = issin ? j0 : (j0 - 192);
    int sdim = jj >> 6;
    float kb = (float)(jj & 63);
    float fr0 = (sdim == 0) ? f0x : ((sdim == 1) ? f0y : f0z);
    float fr1 = (sdim == 0) ? f1x : ((sdim == 1) ? f1y : f1z);
    ushort8v o0, o1;
#pragma unroll
    for (int i = 0; i < 8; ++i){
      float kf = kb + (float)i;
      float q0 = fr0 * kf; q0 -= floorf(q0);
      float q1 = fr1 * kf; q1 -= floorf(q1);
      float a0 = q0 * 6.2831853071795864f;
      float a1 = q1 * 6.2831853071795864f;
      float v0 = issin ? __sinf(a0) : __cosf(a0);
      float v1 = issin ? __sinf(a1) : __cosf(a1);
      o0[i] = f2bf(v0); o1[i] = f2bf(v1);
    }
    *(ushort8v*)a_d0 = o0;
    *(ushort8v*)a_d1 = o1;
    gll16(W1T + btb0 + k0, b_d0);
    gll16(W1T + btb1 + k0, b_d1);
    __syncthreads();
    mfma_step(As, Bs, acc, lm, quad, wM, wN);
    __syncthreads();
  }
  {                                    // step 28: le (9 vals) + zero pad
    int k0 = 896;
    ushort8v o0, o1;
#pragma unroll
    for (int i = 0; i < 8; ++i){
      int c = cA + i;
      float v0 = (c < 9) ? ltl[g0*9 + c] : 0.0f;
      float v1 = (c < 9) ? ltl[g1*9 + c] : 0.0f;
      o0[i] = f2bf(v0); o1[i] = f2bf(v1);
    }
    *(ushort8v*)a_d0 = o0;
    *(ushort8v*)a_d1 = o1;
    gll16(W1T + btb0 + k0, b_d0);
    gll16(W1T + btb1 + k0, b_d1);
    __syncthreads();
    mfma_step(As, Bs, acc, lm, quad, wM, wN);
  }
  // epilogue: + be1, silu, bf16 store  (C/D: row=quad*4+reg, col=lane&15)
  int mbase = bM*128 + wM + quad*4;
  int nbase = bN*128 + wN + lm;
#pragma unroll
  for (int mi = 0; mi < 4; ++mi)
#pragma unroll
    for (int r = 0; r < 4; ++r){
      int m = mbase + mi*16 + r;
#pragma unroll
      for (int ni = 0; ni < 4; ++ni){
        int n = nbase + ni*16;
        float v = acc[mi][ni][r] + be1[n];
        e1[(size_t)m*256 + n] = f2bf(siluf(v));
      }
    }
}

// ---------------- generic bf16 GEMM, A[M,K] x B^T[256,K], 3 epilogues ----------------
// MODE 0: silu(+bias) -> bf16 store to out_bf [*,256]
// MODE 1: silu(+bias) -> atomicAdd into out_f[src[m]*256+n]  (scatter-sum)
// MODE 2: silu(+bias) + resid -> fp32 store to out_f if m < mlimit
template<int MODE>
__global__ __launch_bounds__(256)
void gemm_bt(const UST* __restrict__ A, const UST* __restrict__ B,
             const float* __restrict__ bias, int K,
             UST* __restrict__ out_bf, float* __restrict__ out_f,
             const int* __restrict__ src, const float* __restrict__ resid,
             int mlimit){
  __shared__ __attribute__((aligned(16))) UST As[128*32];
  __shared__ __attribute__((aligned(16))) UST Bs[128*32];
  int t = threadIdx.x;
  int bM = blockIdx.x, bN = blockIdx.y;
  int rA = t >> 2, cA = (t & 3) * 8;
  size_t ab0 = (size_t)(bM*128 + rA)*K + cA;
  size_t ab1 = ab0 + (size_t)64*K;
  size_t bb0 = (size_t)(bN*128 + rA)*K + cA;
  size_t bb1 = bb0 + (size_t)64*K;
  int lane = t & 63, lm = lane & 15, quad = lane >> 4;
  int wave = t >> 6, wM = (wave >> 1)*64, wN = (wave & 1)*64;
  floatx4 acc[4][4] = {};
  UST* a_d0 = &As[rA*32 + cA];
  UST* a_d1 = &As[(64+rA)*32 + cA];
  UST* b_d0 = &Bs[rA*32 + cA];
  UST* b_d1 = &Bs[(64+rA)*32 + cA];
#pragma unroll 1
  for (int k0 = 0; k0 < K; k0 += 32){
    gll16(A + ab0 + k0, a_d0);
    gll16(A + ab1 + k0, a_d1);
    gll16(B + bb0 + k0, b_d0);
    gll16(B + bb1 + k0, b_d1);
    __syncthreads();
    mfma_step(As, Bs, acc, lm, quad, wM, wN);
    __syncthreads();
  }
  int mbase = bM*128 + wM + quad*4;
  int nbase = bN*128 + wN + lm;
#pragma unroll
  for (int mi = 0; mi < 4; ++mi)
#pragma unroll
    for (int r = 0; r < 4; ++r){
      int m = mbase + mi*16 + r;
      int sidx = 0;
      if (MODE == 1) sidx = src[m];
#pragma unroll
      for (int ni = 0; ni < 4; ++ni){
        int n = nbase + ni*16;
        float v = acc[mi][ni][r] + bias[n];
        v = siluf(v);
        if (MODE == 0){
          out_bf[(size_t)m*256 + n] = f2bf(v);
        } else if (MODE == 1){
          atomicAdd(&out_f[(size_t)sidx*256 + n], v);
        } else {
          if (m < mlimit) out_f[(size_t)m*256 + n] = resid[(size_t)m*256 + n] + v;
        }
      }
    }
}

// ---------------- build yA = [h | agg] bf16, rows padded to M_PAD ----------------
__global__ __launch_bounds__(256) void build_yA(const UST* __restrict__ h,
    const float* __restrict__ sums, const float* __restrict__ cnt,
    UST* __restrict__ yA){
  int i = blockIdx.x*256 + threadIdx.x;     // over M_PAD*128 quads
  int row = i >> 7, q = i & 127;
  ushort4v v = {0, 0, 0, 0};
  if (row < N_NODES){
    if (q < 64){
      v = *(const ushort4v*)(h + (size_t)row*256 + q*4);
    } else {
      float inv = 1.0f / fmaxf(cnt[row], 1.0f);
      float4 s = ((const float4*)(sums + (size_t)row*256))[q - 64];
      v[0] = f2bf(s.x*inv); v[1] = f2bf(s.y*inv);
      v[2] = f2bf(s.z*inv); v[3] = f2bf(s.w*inv);
    }
  }
  *(ushort4v*)(yA + (size_t)row*512 + q*4) = v;
}

extern "C" void kernel_launch(void* const* d_in, const int* in_sizes, int n_in,
                              void* d_out, int out_size, void* d_ws, size_t ws_size,
                              hipStream_t stream){
  (void)in_sizes; (void)n_in; (void)out_size; (void)ws_size;
  const float* node_features = (const float*)d_in[0];
  const float* lattices      = (const float*)d_in[1];
  const int*   edge_index    = (const int*)d_in[2];   // [2,E]: row0=src, row1=dst
  const int*   edge2graph    = (const int*)d_in[3];
  const float* frac_diff     = (const float*)d_in[4];
  const float* ln_gamma      = (const float*)d_in[6];
  const float* ln_beta       = (const float*)d_in[7];
  const float* We1 = (const float*)d_in[8];
  const float* be1 = (const float*)d_in[9];
  const float* We2 = (const float*)d_in[10];
  const float* be2 = (const float*)d_in[11];
  const float* Wn1 = (const float*)d_in[12];
  const float* bn1 = (const float*)d_in[13];
  const float* Wn2 = (const float*)d_in[14];
  const float* bn2 = (const float*)d_in[15];

  char* w = (char*)d_ws;
  size_t off = 0;
  auto carve = [&](size_t bytes) -> char* {
    char* p = w + off; off += (bytes + 1023) & ~(size_t)1023; return p;
  };
  UST*   W1T  = (UST*)carve((size_t)256*KE*2);
  UST*   W2T  = (UST*)carve((size_t)256*256*2);
  UST*   Wn1T = (UST*)carve((size_t)256*512*2);
  UST*   Wn2T = (UST*)carve((size_t)256*256*2);
  UST*   hbf  = (UST*)carve((size_t)N_NODES*256*2);
  float* ltl  = (float*)carve((size_t)9000*4);
  float* cnt  = (float*)carve((size_t)N_NODES*4);
  float* sums = (float*)carve((size_t)N_NODES*256*4);
  UST*   e1   = (UST*)carve((size_t)E_EDGES*256*2);
  UST*   yA   = (UST*)carve((size_t)M_PAD*512*2);
  UST*   t1   = (UST*)carve((size_t)M_PAD*256*2);

  hipMemsetAsync(sums, 0, (size_t)N_NODES*256*4, stream);
  hipMemsetAsync(cnt,  0, (size_t)N_NODES*4, stream);

  prep_w<<<928, 256, 0, stream>>>(We1, We2, Wn1, Wn2, W1T, W2T, Wn1T, Wn2T);
  ln_kernel<<<N_NODES/4, 256, 0, stream>>>(node_features, ln_gamma, ln_beta, hbf);
  ltl_kernel<<<36, 256, 0, stream>>>(lattices, ltl);
  cnt_kernel<<<E_EDGES/256, 256, 0, stream>>>(edge_index, cnt);

  gemm_edge1<<<dim3(E_EDGES/128, 2), 256, 0, stream>>>(
      hbf, edge_index, edge2graph, frac_diff, ltl, W1T, be1, e1);

  gemm_bt<1><<<dim3(E_EDGES/128, 2), 256, 0, stream>>>(
      e1, W2T, be2, 256, nullptr, sums, edge_index, nullptr, 0);

  build_yA<<<(M_PAD*128)/256, 256, 0, stream>>>(hbf, sums, cnt, yA);

  gemm_bt<0><<<dim3(M_PAD/128, 2), 256, 0, stream>>>(
      yA, Wn1T, bn1, 512, t1, nullptr, nullptr, nullptr, 0);

  gemm_bt<2><<<dim3(M_PAD/128, 2), 256, 0, stream>>>(
      t1, Wn2T, bn2, 256, nullptr, (float*)d_out, nullptr, node_features, N_NODES);
}

// Round 2
// 647.604 us; speedup vs baseline: 1.1251x; 1.1251x over previous
//
#include <hip/hip_runtime.h>

typedef unsigned short UST;
typedef __bf16 bf16x8 __attribute__((ext_vector_type(8)));
typedef float floatx4 __attribute__((ext_vector_type(4)));
typedef unsigned short ushort8v __attribute__((ext_vector_type(8)));
typedef unsigned short ushort4v __attribute__((ext_vector_type(4)));

#define N_NODES 20000
#define E_EDGES 320000
#define KE 928         // padded edge-MLP K: [hi 0:256 | hj 256:512 | fd 512:896 | le 896:905 | 0 pad:928]
#define M_PAD 20096    // 157*128

static __device__ __forceinline__ UST f2bf(float x){
  unsigned int u = __float_as_uint(x);
  u += 0x7fffu + ((u >> 16) & 1u);   // round-to-nearest-even
  return (UST)(u >> 16);
}
static __device__ __forceinline__ float bf2f(UST u){
  return __uint_as_float(((unsigned int)u) << 16);
}
static __device__ __forceinline__ float siluf(float v){
  return v / (1.0f + __expf(-v));
}
// async global->LDS, 16B per lane; LDS dest must be wave-uniform-base + lane*16
static __device__ __forceinline__ void gll16(const void* g, void* lds){
  __builtin_amdgcn_global_load_lds(
      (const __attribute__((address_space(1))) unsigned int*)g,
      (__attribute__((address_space(3))) unsigned int*)lds, 16, 0, 0);
}

static __device__ __forceinline__ void mfma_step(const UST* As, const UST* Bs,
    floatx4 (&acc)[4][4], int lm, int quad, int wM, int wN){
  bf16x8 a[4], b[4];
#pragma unroll
  for (int i = 0; i < 4; ++i)
    a[i] = *(const bf16x8*)(As + (wM + i*16 + lm)*32 + quad*8);
#pragma unroll
  for (int i = 0; i < 4; ++i)
    b[i] = *(const bf16x8*)(Bs + (wN + i*16 + lm)*32 + quad*8);
#pragma unroll
  for (int mi = 0; mi < 4; ++mi)
#pragma unroll
    for (int ni = 0; ni < 4; ++ni)
      acc[mi][ni] = __builtin_amdgcn_mfma_f32_16x16x32_bf16(a[mi], b[ni], acc[mi][ni], 0, 0, 0);
}

// ---------------- LayerNorm: one wave per row, h -> bf16 ----------------
__global__ __launch_bounds__(256) void ln_kernel(const float* __restrict__ x,
    const float* __restrict__ gamma, const float* __restrict__ beta,
    UST* __restrict__ h){
  int wave = threadIdx.x >> 6, lane = threadIdx.x & 63;
  int row = blockIdx.x * 4 + wave;
  const float4* xp = (const float4*)(x + (size_t)row * 256);
  float4 v = xp[lane];
  float s  = v.x + v.y + v.z + v.w;
  float sq = v.x*v.x + v.y*v.y + v.z*v.z + v.w*v.w;
#pragma unroll
  for (int o = 32; o > 0; o >>= 1){ s += __shfl_xor(s, o); sq += __shfl_xor(sq, o); }
  float mu  = s * (1.0f/256.0f);
  float var = sq * (1.0f/256.0f) - mu*mu;
  float rs  = rsqrtf(var + 1e-5f);
  float4 g = ((const float4*)gamma)[lane];
  float4 b = ((const float4*)beta)[lane];
  ushort4v o4;
  o4[0] = f2bf((v.x-mu)*rs*g.x + b.x);
  o4[1] = f2bf((v.y-mu)*rs*g.y + b.y);
  o4[2] = f2bf((v.z-mu)*rs*g.z + b.z);
  o4[3] = f2bf((v.w-mu)*rs*g.w + b.w);
  *(ushort4v*)(h + (size_t)row*256 + lane*4) = o4;
}

// ---------------- ltl = L @ L^T per graph ----------------
__global__ __launch_bounds__(256) void ltl_kernel(const float* __restrict__ lat,
                                                  float* __restrict__ ltl){
  int i = blockIdx.x*256 + threadIdx.x;
  if (i >= 9000) return;
  int g = i / 9, ij = i % 9, a = ij / 3, b = ij % 3;
  const float* L = lat + g*9;
  ltl[i] = L[a*3+0]*L[b*3+0] + L[a*3+1]*L[b*3+1] + L[a*3+2]*L[b*3+2];
}

// ---------------- weight prep: transpose -> bf16 (We1 rows permuted) ----------------
__global__ __launch_bounds__(256) void prep_w(const float* __restrict__ We1,
    const float* __restrict__ We2, const float* __restrict__ Wn1,
    const float* __restrict__ Wn2, UST* __restrict__ W1T, UST* __restrict__ W2T,
    UST* __restrict__ Wn1T, UST* __restrict__ Wn2T){
  int i = blockIdx.x*256 + threadIdx.x;
  if (i < 256*KE){
    int n = i / KE, k = i % KE;
    float v = 0.0f;
    if (k < 512)      v = We1[(size_t)k*256 + n];          // hi|hj
    else if (k < 896) v = We1[(size_t)(k+9)*256 + n];      // fd (orig rows 521..904)
    else if (k < 905) v = We1[(size_t)(k-384)*256 + n];    // le (orig rows 512..520)
    W1T[i] = f2bf(v);
  }
  if (i < 256*256){
    int n = i >> 8, k = i & 255;
    W2T[i]  = f2bf(We2[(size_t)k*256 + n]);
    Wn2T[i] = f2bf(Wn2[(size_t)k*256 + n]);
  }
  if (i < 256*512){
    int n = i >> 9, k = i & 511;
    Wn1T[i] = f2bf(Wn1[(size_t)k*256 + n]);
  }
}

// ---------------- CSR build: histogram -> scan -> fill ----------------
__global__ __launch_bounds__(256) void cnt_kernel(const int* __restrict__ src,
                                                  int* __restrict__ cnti){
  int e = blockIdx.x*256 + threadIdx.x;
  if (e < E_EDGES) atomicAdd(&cnti[src[e]], 1);
}

__global__ __launch_bounds__(256) void scan_kernel(const int* __restrict__ cnti,
    int* __restrict__ off, int* __restrict__ head){
  __shared__ int ps[256];
  int t = threadIdx.x;
  const int CH = 79;                       // 256*79 = 20224 >= 20000
  int base = t * CH;
  int s = 0;
#pragma unroll 1
  for (int i = 0; i < CH; ++i){ int idx = base + i; if (idx < N_NODES) s += cnti[idx]; }
  ps[t] = s; __syncthreads();
#pragma unroll 1
  for (int o = 1; o < 256; o <<= 1){
    int v = (t >= o) ? ps[t - o] : 0;
    __syncthreads();
    ps[t] += v;
    __syncthreads();
  }
  int run = (t > 0) ? ps[t-1] : 0;
#pragma unroll 1
  for (int i = 0; i < CH; ++i){
    int idx = base + i;
    if (idx < N_NODES){ off[idx] = run; head[idx] = run; run += cnti[idx]; }
  }
  if (t == 255) off[N_NODES] = run;
}

__global__ __launch_bounds__(256) void fill_kernel(const int* __restrict__ src,
    int* __restrict__ head, int* __restrict__ eidx){
  int e = blockIdx.x*256 + threadIdx.x;
  if (e < E_EDGES){
    int p = atomicAdd(&head[src[e]], 1);
    eidx[p] = e;
  }
}

// ---------------- GEMM1: fused x-construction, e1 = silu(x @ We1 + be1) ----------------
__global__ __launch_bounds__(256)
void gemm_edge1(const UST* __restrict__ h, const int* __restrict__ ei,
                const int* __restrict__ e2g, const float* __restrict__ fdif,
                const float* __restrict__ ltl, const UST* __restrict__ W1T,
                const float* __restrict__ be1, UST* __restrict__ e1){
  __shared__ __attribute__((aligned(16))) UST As[128*32];
  __shared__ __attribute__((aligned(16))) UST Bs[128*32];
  int t = threadIdx.x;
  int bM = blockIdx.x, bN = blockIdx.y;
  int rA = t >> 2, cA = (t & 3) * 8;
  int r0 = bM*128 + rA, r1 = r0 + 64;
  int src0 = ei[r0], src1 = ei[r1];
  int dst0 = ei[E_EDGES + r0], dst1 = ei[E_EDGES + r1];
  int g0 = e2g[r0], g1 = e2g[r1];
  float f0x = fdif[r0*3+0], f0y = fdif[r0*3+1], f0z = fdif[r0*3+2];
  float f1x = fdif[r1*3+0], f1y = fdif[r1*3+1], f1z = fdif[r1*3+2];
  size_t btb0 = (size_t)(bN*128 + rA)*KE + cA;
  size_t btb1 = btb0 + (size_t)64*KE;
  int lane = t & 63, lm = lane & 15, quad = lane >> 4;
  int wave = t >> 6, wM = (wave >> 1)*64, wN = (wave & 1)*64;
  floatx4 acc[4][4] = {};
  UST* a_d0 = &As[rA*32 + cA];
  UST* a_d1 = &As[(64+rA)*32 + cA];
  UST* b_d0 = &Bs[rA*32 + cA];
  UST* b_d1 = &Bs[(64+rA)*32 + cA];

  int step = 0;
#pragma unroll 1
  for (; step < 8; ++step){            // hi: gather h[src]
    int k0 = step*32;
    gll16(h + (size_t)src0*256 + k0 + cA, a_d0);
    gll16(h + (size_t)src1*256 + k0 + cA, a_d1);
    gll16(W1T + btb0 + k0, b_d0);
    gll16(W1T + btb1 + k0, b_d1);
    __syncthreads();
    mfma_step(As, Bs, acc, lm, quad, wM, wN);
    __syncthreads();
  }
#pragma unroll 1
  for (; step < 16; ++step){           // hj: gather h[dst]
    int k0 = step*32;
    int kk = k0 - 256 + cA;
    gll16(h + (size_t)dst0*256 + kk, a_d0);
    gll16(h + (size_t)dst1*256 + kk, a_d1);
    gll16(W1T + btb0 + k0, b_d0);
    gll16(W1T + btb1 + k0, b_d1);
    __syncthreads();
    mfma_step(As, Bs, acc, lm, quad, wM, wN);
    __syncthreads();
  }
#pragma unroll 1
  for (; step < 28; ++step){           // fd: sin/cos(2*pi*frac*k)
    int k0 = step*32;
    int j0 = k0 - 512 + cA;
    bool issin = j0 < 192;
    int jj = issin ? j0 : (j0 - 192);
    int sdim = jj >> 6;
    float kb = (float)(jj & 63);
    float fr0 = (sdim == 0) ? f0x : ((sdim == 1) ? f0y : f0z);
    float fr1 = (sdim == 0) ? f1x : ((sdim == 1) ? f1y : f1z);
    ushort8v o0, o1;
#pragma unroll
    for (int i = 0; i < 8; ++i){
      float kf = kb + (float)i;
      float q0 = fr0 * kf; q0 -= floorf(q0);
      float q1 = fr1 * kf; q1 -= floorf(q1);
      float a0 = q0 * 6.2831853071795864f;
      float a1 = q1 * 6.2831853071795864f;
      float v0 = issin ? __sinf(a0) : __cosf(a0);
      float v1 = issin ? __sinf(a1) : __cosf(a1);
      o0[i] = f2bf(v0); o1[i] = f2bf(v1);
    }
    *(ushort8v*)a_d0 = o0;
    *(ushort8v*)a_d1 = o1;
    gll16(W1T + btb0 + k0, b_d0);
    gll16(W1T + btb1 + k0, b_d1);
    __syncthreads();
    mfma_step(As, Bs, acc, lm, quad, wM, wN);
    __syncthreads();
  }
  {                                    // step 28: le (9 vals) + zero pad
    int k0 = 896;
    ushort8v o0, o1;
#pragma unroll
    for (int i = 0; i < 8; ++i){
      int c = cA + i;
      float v0 = (c < 9) ? ltl[g0*9 + c] : 0.0f;
      float v1 = (c < 9) ? ltl[g1*9 + c] : 0.0f;
      o0[i] = f2bf(v0); o1[i] = f2bf(v1);
    }
    *(ushort8v*)a_d0 = o0;
    *(ushort8v*)a_d1 = o1;
    gll16(W1T + btb0 + k0, b_d0);
    gll16(W1T + btb1 + k0, b_d1);
    __syncthreads();
    mfma_step(As, Bs, acc, lm, quad, wM, wN);
  }
  // epilogue: + be1, silu, bf16 store  (C/D: row=quad*4+reg, col=lane&15)
  int mbase = bM*128 + wM + quad*4;
  int nbase = bN*128 + wN + lm;
#pragma unroll
  for (int mi = 0; mi < 4; ++mi)
#pragma unroll
    for (int r = 0; r < 4; ++r){
      int m = mbase + mi*16 + r;
#pragma unroll
      for (int ni = 0; ni < 4; ++ni){
        int n = nbase + ni*16;
        float v = acc[mi][ni][r] + be1[n];
        e1[(size_t)m*256 + n] = f2bf(siluf(v));
      }
    }
}

// ---------------- generic bf16 GEMM, A[M,K] x B^T[256,K], 2 epilogues ----------------
// MODE 0: silu(+bias) -> bf16 store to out_bf [*,256]  (may alias A in-place:
//         each block reads only its own 128 rows, all reads precede the store)
// MODE 2: silu(+bias) + resid -> fp32 store to out_f if m < mlimit
template<int MODE>
__global__ __launch_bounds__(256)
void gemm_bt(const UST* __restrict__ A, const UST* __restrict__ B,
             const float* __restrict__ bias, int K,
             UST* __restrict__ out_bf, float* __restrict__ out_f,
             const float* __restrict__ resid, int mlimit){
  __shared__ __attribute__((aligned(16))) UST As[128*32];
  __shared__ __attribute__((aligned(16))) UST Bs[128*32];
  int t = threadIdx.x;
  int bM = blockIdx.x, bN = blockIdx.y;
  int rA = t >> 2, cA = (t & 3) * 8;
  size_t ab0 = (size_t)(bM*128 + rA)*K + cA;
  size_t ab1 = ab0 + (size_t)64*K;
  size_t bb0 = (size_t)(bN*128 + rA)*K + cA;
  size_t bb1 = bb0 + (size_t)64*K;
  int lane = t & 63, lm = lane & 15, quad = lane >> 4;
  int wave = t >> 6, wM = (wave >> 1)*64, wN = (wave & 1)*64;
  floatx4 acc[4][4] = {};
  UST* a_d0 = &As[rA*32 + cA];
  UST* a_d1 = &As[(64+rA)*32 + cA];
  UST* b_d0 = &Bs[rA*32 + cA];
  UST* b_d1 = &Bs[(64+rA)*32 + cA];
#pragma unroll 1
  for (int k0 = 0; k0 < K; k0 += 32){
    gll16(A + ab0 + k0, a_d0);
    gll16(A + ab1 + k0, a_d1);
    gll16(B + bb0 + k0, b_d0);
    gll16(B + bb1 + k0, b_d1);
    __syncthreads();
    mfma_step(As, Bs, acc, lm, quad, wM, wN);
    __syncthreads();
  }
  int mbase = bM*128 + wM + quad*4;
  int nbase = bN*128 + wN + lm;
#pragma unroll
  for (int mi = 0; mi < 4; ++mi)
#pragma unroll
    for (int r = 0; r < 4; ++r){
      int m = mbase + mi*16 + r;
#pragma unroll
      for (int ni = 0; ni < 4; ++ni){
        int n = nbase + ni*16;
        float v = acc[mi][ni][r] + bias[n];
        v = siluf(v);
        if (MODE == 0){
          out_bf[(size_t)m*256 + n] = f2bf(v);
        } else {
          if (m < mlimit) out_f[(size_t)m*256 + n] = resid[(size_t)m*256 + n] + v;
        }
      }
    }
}

// ---------------- aggregate: per node, gather CSR edges, mean; build yA ----------------
__global__ __launch_bounds__(256) void agg_kernel(const UST* __restrict__ e2,
    const int* __restrict__ off, const int* __restrict__ eidx,
    const UST* __restrict__ h, UST* __restrict__ yA){
  int row = blockIdx.x;          // 0..M_PAD-1
  int t = threadIdx.x;           // col 0..255
  UST hv = 0, av = 0;
  if (row < N_NODES){
    hv = h[(size_t)row*256 + t];
    int s = off[row], e = off[row+1];
    float sum = 0.0f, sum2 = 0.0f;
    int i = s;
#pragma unroll 1
    for (; i + 1 < e; i += 2){
      int ea = eidx[i], eb = eidx[i+1];
      sum  += bf2f(e2[(size_t)ea*256 + t]);
      sum2 += bf2f(e2[(size_t)eb*256 + t]);
    }
    if (i < e) sum += bf2f(e2[(size_t)eidx[i]*256 + t]);
    sum += sum2;
    float inv = 1.0f / fmaxf((float)(e - s), 1.0f);
    av = f2bf(sum * inv);
  }
  yA[(size_t)row*512 + t]       = hv;
  yA[(size_t)row*512 + 256 + t] = av;
}

extern "C" void kernel_launch(void* const* d_in, const int* in_sizes, int n_in,
                              void* d_out, int out_size, void* d_ws, size_t ws_size,
                              hipStream_t stream){
  (void)in_sizes; (void)n_in; (void)out_size; (void)ws_size;
  const float* node_features = (const float*)d_in[0];
  const float* lattices      = (const float*)d_in[1];
  const int*   edge_index    = (const int*)d_in[2];   // [2,E]: row0=src, row1=dst
  const int*   edge2graph    = (const int*)d_in[3];
  const float* frac_diff     = (const float*)d_in[4];
  const float* ln_gamma      = (const float*)d_in[6];
  const float* ln_beta       = (const float*)d_in[7];
  const float* We1 = (const float*)d_in[8];
  const float* be1 = (const float*)d_in[9];
  const float* We2 = (const float*)d_in[10];
  const float* be2 = (const float*)d_in[11];
  const float* Wn1 = (const float*)d_in[12];
  const float* bn1 = (const float*)d_in[13];
  const float* Wn2 = (const float*)d_in[14];
  const float* bn2 = (const float*)d_in[15];

  char* w = (char*)d_ws;
  size_t off_b = 0;
  auto carve = [&](size_t bytes) -> char* {
    char* p = w + off_b; off_b += (bytes + 1023) & ~(size_t)1023; return p;
  };
  UST*   W1T  = (UST*)carve((size_t)256*KE*2);
  UST*   W2T  = (UST*)carve((size_t)256*256*2);
  UST*   Wn1T = (UST*)carve((size_t)256*512*2);
  UST*   Wn2T = (UST*)carve((size_t)256*256*2);
  UST*   hbf  = (UST*)carve((size_t)N_NODES*256*2);
  float* ltl  = (float*)carve((size_t)9000*4);
  int*   cnti = (int*)carve((size_t)N_NODES*4);
  int*   offs = (int*)carve((size_t)(N_NODES+1)*4);
  int*   head = (int*)carve((size_t)N_NODES*4);
  int*   eidx = (int*)carve((size_t)E_EDGES*4);
  UST*   e1   = (UST*)carve((size_t)E_EDGES*256*2);
  UST*   yA   = (UST*)carve((size_t)M_PAD*512*2);
  UST*   t1   = (UST*)carve((size_t)M_PAD*256*2);

  hipMemsetAsync(cnti, 0, (size_t)N_NODES*4, stream);

  prep_w<<<928, 256, 0, stream>>>(We1, We2, Wn1, Wn2, W1T, W2T, Wn1T, Wn2T);
  ln_kernel<<<N_NODES/4, 256, 0, stream>>>(node_features, ln_gamma, ln_beta, hbf);
  ltl_kernel<<<36, 256, 0, stream>>>(lattices, ltl);

  cnt_kernel<<<E_EDGES/256, 256, 0, stream>>>(edge_index, cnti);
  scan_kernel<<<1, 256, 0, stream>>>(cnti, offs, head);
  fill_kernel<<<E_EDGES/256, 256, 0, stream>>>(edge_index, head, eidx);

  gemm_edge1<<<dim3(E_EDGES/128, 2), 256, 0, stream>>>(
      hbf, edge_index, edge2graph, frac_diff, ltl, W1T, be1, e1);

  // edge MLP2, in-place over e1 (each block reads only its own rows)
  gemm_bt<0><<<dim3(E_EDGES/128, 2), 256, 0, stream>>>(
      e1, W2T, be2, 256, e1, nullptr, nullptr, 0);

  agg_kernel<<<M_PAD, 256, 0, stream>>>(e1, offs, eidx, hbf, yA);

  gemm_bt<0><<<dim3(M_PAD/128, 2), 256, 0, stream>>>(
      yA, Wn1T, bn1, 512, t1, nullptr, nullptr, 0);

  gemm_bt<2><<<dim3(M_PAD/128, 2), 256, 0, stream>>>(
      t1, Wn2T, bn2, 256, nullptr, (float*)d_out, node_features, N_NODES);
}

// Round 3
// 601.434 us; speedup vs baseline: 1.2115x; 1.0768x over previous
//
#include <hip/hip_runtime.h>

typedef unsigned short UST;
typedef __bf16 bf16x8 __attribute__((ext_vector_type(8)));
typedef float floatx4 __attribute__((ext_vector_type(4)));
typedef unsigned short ushort8v __attribute__((ext_vector_type(8)));
typedef unsigned short ushort4v __attribute__((ext_vector_type(4)));

#define N_NODES 20000
#define E_EDGES 320000
#define KE 928         // padded edge-MLP K: [hi 0:256 | hj 256:512 | fd 512:896 | le 896:905 | 0 pad:928]
#define M_PAD 20096    // 157*128

static __device__ __forceinline__ UST f2bf(float x){
  unsigned int u = __float_as_uint(x);
  u += 0x7fffu + ((u >> 16) & 1u);   // round-to-nearest-even
  return (UST)(u >> 16);
}
static __device__ __forceinline__ float bf2f(UST u){
  return __uint_as_float(((unsigned int)u) << 16);
}
static __device__ __forceinline__ float siluf(float v){
  return v / (1.0f + __expf(-v));
}
// async global->LDS, 16B per lane; LDS dest must be wave-uniform base + lane*16
static __device__ __forceinline__ void gll16(const void* g, void* lds){
  __builtin_amdgcn_global_load_lds(
      (const __attribute__((address_space(1))) unsigned int*)g,
      (__attribute__((address_space(3))) unsigned int*)lds, 16, 0, 0);
}

// As: 128 rows x 32 cols. Bs: 256 rows x 32 cols. Wave computes 64x64 at (wM,wN).
static __device__ __forceinline__ void mfma_step(const UST* As, const UST* Bs,
    floatx4 (&acc)[4][4], int lm, int quad, int wM, int wN){
  bf16x8 a[4], b[4];
#pragma unroll
  for (int i = 0; i < 4; ++i)
    a[i] = *(const bf16x8*)(As + (wM + i*16 + lm)*32 + quad*8);
#pragma unroll
  for (int i = 0; i < 4; ++i)
    b[i] = *(const bf16x8*)(Bs + (wN + i*16 + lm)*32 + quad*8);
#pragma unroll
  for (int mi = 0; mi < 4; ++mi)
#pragma unroll
    for (int ni = 0; ni < 4; ++ni)
      acc[mi][ni] = __builtin_amdgcn_mfma_f32_16x16x32_bf16(a[mi], b[ni], acc[mi][ni], 0, 0, 0);
}

// ---------------- LayerNorm: one wave per row, h -> bf16 ----------------
__global__ __launch_bounds__(256) void ln_kernel(const float* __restrict__ x,
    const float* __restrict__ gamma, const float* __restrict__ beta,
    UST* __restrict__ h){
  int wave = threadIdx.x >> 6, lane = threadIdx.x & 63;
  int row = blockIdx.x * 4 + wave;
  const float4* xp = (const float4*)(x + (size_t)row * 256);
  float4 v = xp[lane];
  float s  = v.x + v.y + v.z + v.w;
  float sq = v.x*v.x + v.y*v.y + v.z*v.z + v.w*v.w;
#pragma unroll
  for (int o = 32; o > 0; o >>= 1){ s += __shfl_xor(s, o); sq += __shfl_xor(sq, o); }
  float mu  = s * (1.0f/256.0f);
  float var = sq * (1.0f/256.0f) - mu*mu;
  float rs  = rsqrtf(var + 1e-5f);
  float4 g = ((const float4*)gamma)[lane];
  float4 b = ((const float4*)beta)[lane];
  ushort4v o4;
  o4[0] = f2bf((v.x-mu)*rs*g.x + b.x);
  o4[1] = f2bf((v.y-mu)*rs*g.y + b.y);
  o4[2] = f2bf((v.z-mu)*rs*g.z + b.z);
  o4[3] = f2bf((v.w-mu)*rs*g.w + b.w);
  *(ushort4v*)(h + (size_t)row*256 + lane*4) = o4;
}

// ---------------- ltl = L @ L^T per graph ----------------
__global__ __launch_bounds__(256) void ltl_kernel(const float* __restrict__ lat,
                                                  float* __restrict__ ltl){
  int i = blockIdx.x*256 + threadIdx.x;
  if (i >= 9000) return;
  int g = i / 9, ij = i % 9, a = ij / 3, b = ij % 3;
  const float* L = lat + g*9;
  ltl[i] = L[a*3+0]*L[b*3+0] + L[a*3+1]*L[b*3+1] + L[a*3+2]*L[b*3+2];
}

// ---------------- weight prep: transpose -> bf16 (We1 rows permuted) ----------------
__global__ __launch_bounds__(256) void prep_w(const float* __restrict__ We1,
    const float* __restrict__ We2, const float* __restrict__ Wn1,
    const float* __restrict__ Wn2, UST* __restrict__ W1T, UST* __restrict__ W2T,
    UST* __restrict__ Wn1T, UST* __restrict__ Wn2T){
  int i = blockIdx.x*256 + threadIdx.x;
  if (i < 256*KE){
    int n = i / KE, k = i % KE;
    float v = 0.0f;
    if (k < 512)      v = We1[(size_t)k*256 + n];          // hi|hj
    else if (k < 896) v = We1[(size_t)(k+9)*256 + n];      // fd (orig rows 521..904)
    else if (k < 905) v = We1[(size_t)(k-384)*256 + n];    // le (orig rows 512..520)
    W1T[i] = f2bf(v);
  }
  if (i < 256*256){
    int n = i >> 8, k = i & 255;
    W2T[i]  = f2bf(We2[(size_t)k*256 + n]);
    Wn2T[i] = f2bf(Wn2[(size_t)k*256 + n]);
  }
  if (i < 256*512){
    int n = i >> 9, k = i & 511;
    Wn1T[i] = f2bf(Wn1[(size_t)k*256 + n]);
  }
}

// ---------------- CSR build: histogram -> scan -> fill ----------------
__global__ __launch_bounds__(256) void cnt_kernel(const int* __restrict__ src,
                                                  int* __restrict__ cnti){
  int e = blockIdx.x*256 + threadIdx.x;
  if (e < E_EDGES) atomicAdd(&cnti[src[e]], 1);
}

__global__ __launch_bounds__(256) void scan_kernel(const int* __restrict__ cnti,
    int* __restrict__ off, int* __restrict__ head){
  __shared__ int ps[256];
  int t = threadIdx.x;
  const int CH = 79;                       // 256*79 = 20224 >= 20000
  int base = t * CH;
  int s = 0;
#pragma unroll 1
  for (int i = 0; i < CH; ++i){ int idx = base + i; if (idx < N_NODES) s += cnti[idx]; }
  ps[t] = s; __syncthreads();
#pragma unroll 1
  for (int o = 1; o < 256; o <<= 1){
    int v = (t >= o) ? ps[t - o] : 0;
    __syncthreads();
    ps[t] += v;
    __syncthreads();
  }
  int run = (t > 0) ? ps[t-1] : 0;
#pragma unroll 1
  for (int i = 0; i < CH; ++i){
    int idx = base + i;
    if (idx < N_NODES){ off[idx] = run; head[idx] = run; run += cnti[idx]; }
  }
  if (t == 255) off[N_NODES] = run;
}

__global__ __launch_bounds__(256) void fill_kernel(const int* __restrict__ src,
    int* __restrict__ head, int* __restrict__ eidx){
  int e = blockIdx.x*256 + threadIdx.x;
  if (e < E_EDGES){
    int p = atomicAdd(&head[src[e]], 1);
    eidx[p] = e;
  }
}

// ---------------- GEMM1: fused x-construction, e1 = silu(x @ We1 + be1) ----------------
// 512 threads, 128x256 tile (full N in one block: A built once per M-tile)
__global__ __launch_bounds__(512)
void gemm_edge1(const UST* __restrict__ h, const int* __restrict__ ei,
                const int* __restrict__ e2g, const float* __restrict__ fdif,
                const float* __restrict__ ltl, const UST* __restrict__ W1T,
                const float* __restrict__ be1, UST* __restrict__ e1){
  __shared__ __attribute__((aligned(16))) UST As[128*32];
  __shared__ __attribute__((aligned(16))) UST Bs[256*32];
  int t = threadIdx.x;
  int bM = blockIdx.x;
  int rA = t >> 2, cA = (t & 3) * 8;       // rA 0..127, one A-row per thread
  int r0 = bM*128 + rA;
  int src0 = ei[r0];
  int dst0 = ei[E_EDGES + r0];
  int g0 = e2g[r0];
  float f0x = fdif[r0*3+0], f0y = fdif[r0*3+1], f0z = fdif[r0*3+2];
  size_t btb0 = (size_t)rA*KE + cA;        // B rows rA and rA+128
  size_t btb1 = btb0 + (size_t)128*KE;
  int lane = t & 63, lm = lane & 15, quad = lane >> 4;
  int wave = t >> 6, wM = (wave >> 2)*64, wN = (wave & 3)*64;
  floatx4 acc[4][4] = {};
  UST* a_d  = &As[rA*32 + cA];
  UST* b_d0 = &Bs[rA*32 + cA];
  UST* b_d1 = &Bs[(128+rA)*32 + cA];

  int step = 0;
#pragma unroll 1
  for (; step < 8; ++step){            // hi: gather h[src]
    int k0 = step*32;
    gll16(h + (size_t)src0*256 + k0 + cA, a_d);
    gll16(W1T + btb0 + k0, b_d0);
    gll16(W1T + btb1 + k0, b_d1);
    __syncthreads();
    mfma_step(As, Bs, acc, lm, quad, wM, wN);
    __syncthreads();
  }
#pragma unroll 1
  for (; step < 16; ++step){           // hj: gather h[dst]
    int k0 = step*32;
    gll16(h + (size_t)dst0*256 + (k0 - 256) + cA, a_d);
    gll16(W1T + btb0 + k0, b_d0);
    gll16(W1T + btb1 + k0, b_d1);
    __syncthreads();
    mfma_step(As, Bs, acc, lm, quad, wM, wN);
    __syncthreads();
  }
#pragma unroll 1
  for (; step < 28; ++step){           // fd: sin/cos(2*pi*frac*k), HW revolution-domain
    int k0 = step*32;
    int j0 = k0 - 512 + cA;
    bool issin = j0 < 192;
    int jj = issin ? j0 : (j0 - 192);
    int sdim = jj >> 6;
    float kb = (float)(jj & 63);
    float fr0 = (sdim == 0) ? f0x : ((sdim == 1) ? f0y : f0z);
    ushort8v o0;
#pragma unroll
    for (int i = 0; i < 8; ++i){
      float q = __builtin_amdgcn_fractf(fr0 * (kb + (float)i));   // revolutions in [0,1)
      float v = issin ? __builtin_amdgcn_sinf(q) : __builtin_amdgcn_cosf(q);
      o0[i] = f2bf(v);
    }
    *(ushort8v*)a_d = o0;
    gll16(W1T + btb0 + k0, b_d0);
    gll16(W1T + btb1 + k0, b_d1);
    __syncthreads();
    mfma_step(As, Bs, acc, lm, quad, wM, wN);
    __syncthreads();
  }
  {                                    // step 28: le (9 vals) + zero pad
    int k0 = 896;
    ushort8v o0;
#pragma unroll
    for (int i = 0; i < 8; ++i){
      int c = cA + i;
      float v0 = (c < 9) ? ltl[g0*9 + c] : 0.0f;
      o0[i] = f2bf(v0);
    }
    *(ushort8v*)a_d = o0;
    gll16(W1T + btb0 + k0, b_d0);
    gll16(W1T + btb1 + k0, b_d1);
    __syncthreads();
    mfma_step(As, Bs, acc, lm, quad, wM, wN);
  }
  // epilogue: + be1, silu, bf16 store  (C/D: row=quad*4+reg, col=lane&15)
  int mbase = bM*128 + wM + quad*4;
  int nbase = wN + lm;
#pragma unroll
  for (int mi = 0; mi < 4; ++mi)
#pragma unroll
    for (int r = 0; r < 4; ++r){
      int m = mbase + mi*16 + r;
#pragma unroll
      for (int ni = 0; ni < 4; ++ni){
        int n = nbase + ni*16;
        float v = acc[mi][ni][r] + be1[n];
        e1[(size_t)m*256 + n] = f2bf(siluf(v));
      }
    }
}

// ---------------- generic bf16 GEMM, A[M,K] x B^T[256,K], 512 thr, 128x256 tile ----
// MODE 0: silu(+bias) -> bf16 store to out_bf (may alias A in-place: block reads
//         only its own 128 rows and all reads precede the epilogue stores)
// MODE 2: silu(+bias) + resid -> fp32 store to out_f if m < mlimit
template<int MODE>
__global__ __launch_bounds__(512)
void gemm_bt(const UST* __restrict__ A, const UST* __restrict__ B,
             const float* __restrict__ bias, int K,
             UST* __restrict__ out_bf, float* __restrict__ out_f,
             const float* __restrict__ resid, int mlimit){
  __shared__ __attribute__((aligned(16))) UST As[128*32];
  __shared__ __attribute__((aligned(16))) UST Bs[256*32];
  int t = threadIdx.x;
  int bM = blockIdx.x;
  int rA = t >> 2, cA = (t & 3) * 8;
  size_t ab0 = (size_t)(bM*128 + rA)*K + cA;
  size_t bb0 = (size_t)rA*K + cA;
  size_t bb1 = bb0 + (size_t)128*K;
  int lane = t & 63, lm = lane & 15, quad = lane >> 4;
  int wave = t >> 6, wM = (wave >> 2)*64, wN = (wave & 3)*64;
  floatx4 acc[4][4] = {};
  UST* a_d  = &As[rA*32 + cA];
  UST* b_d0 = &Bs[rA*32 + cA];
  UST* b_d1 = &Bs[(128+rA)*32 + cA];
#pragma unroll 1
  for (int k0 = 0; k0 < K; k0 += 32){
    gll16(A + ab0 + k0, a_d);
    gll16(B + bb0 + k0, b_d0);
    gll16(B + bb1 + k0, b_d1);
    __syncthreads();
    mfma_step(As, Bs, acc, lm, quad, wM, wN);
    __syncthreads();
  }
  int mbase = bM*128 + wM + quad*4;
  int nbase = wN + lm;
#pragma unroll
  for (int mi = 0; mi < 4; ++mi)
#pragma unroll
    for (int r = 0; r < 4; ++r){
      int m = mbase + mi*16 + r;
#pragma unroll
      for (int ni = 0; ni < 4; ++ni){
        int n = nbase + ni*16;
        float v = acc[mi][ni][r] + bias[n];
        v = siluf(v);
        if (MODE == 0){
          out_bf[(size_t)m*256 + n] = f2bf(v);
        } else {
          if (m < mlimit) out_f[(size_t)m*256 + n] = resid[(size_t)m*256 + n] + v;
        }
      }
    }
}

// ---------------- aggregate: per node, gather CSR edges, mean; build yA ----------------
__global__ __launch_bounds__(256) void agg_kernel(const UST* __restrict__ e2,
    const int* __restrict__ off, const int* __restrict__ eidx,
    const UST* __restrict__ h, UST* __restrict__ yA){
  int row = blockIdx.x;          // 0..M_PAD-1
  int t = threadIdx.x;           // col 0..255
  UST hv = 0, av = 0;
  if (row < N_NODES){
    hv = h[(size_t)row*256 + t];
    int s = off[row], e = off[row+1];
    float sum = 0.0f, sum2 = 0.0f;
    int i = s;
#pragma unroll 1
    for (; i + 1 < e; i += 2){
      int ea = eidx[i], eb = eidx[i+1];
      sum  += bf2f(e2[(size_t)ea*256 + t]);
      sum2 += bf2f(e2[(size_t)eb*256 + t]);
    }
    if (i < e) sum += bf2f(e2[(size_t)eidx[i]*256 + t]);
    sum += sum2;
    float inv = 1.0f / fmaxf((float)(e - s), 1.0f);
    av = f2bf(sum * inv);
  }
  yA[(size_t)row*512 + t]       = hv;
  yA[(size_t)row*512 + 256 + t] = av;
}

extern "C" void kernel_launch(void* const* d_in, const int* in_sizes, int n_in,
                              void* d_out, int out_size, void* d_ws, size_t ws_size,
                              hipStream_t stream){
  (void)in_sizes; (void)n_in; (void)out_size; (void)ws_size;
  const float* node_features = (const float*)d_in[0];
  const float* lattices      = (const float*)d_in[1];
  const int*   edge_index    = (const int*)d_in[2];   // [2,E]: row0=src, row1=dst
  const int*   edge2graph    = (const int*)d_in[3];
  const float* frac_diff     = (const float*)d_in[4];
  const float* ln_gamma      = (const float*)d_in[6];
  const float* ln_beta       = (const float*)d_in[7];
  const float* We1 = (const float*)d_in[8];
  const float* be1 = (const float*)d_in[9];
  const float* We2 = (const float*)d_in[10];
  const float* be2 = (const float*)d_in[11];
  const float* Wn1 = (const float*)d_in[12];
  const float* bn1 = (const float*)d_in[13];
  const float* Wn2 = (const float*)d_in[14];
  const float* bn2 = (const float*)d_in[15];

  char* w = (char*)d_ws;
  size_t off_b = 0;
  auto carve = [&](size_t bytes) -> char* {
    char* p = w + off_b; off_b += (bytes + 1023) & ~(size_t)1023; return p;
  };
  UST*   W1T  = (UST*)carve((size_t)256*KE*2);
  UST*   W2T  = (UST*)carve((size_t)256*256*2);
  UST*   Wn1T = (UST*)carve((size_t)256*512*2);
  UST*   Wn2T = (UST*)carve((size_t)256*256*2);
  UST*   hbf  = (UST*)carve((size_t)N_NODES*256*2);
  float* ltl  = (float*)carve((size_t)9000*4);
  int*   cnti = (int*)carve((size_t)N_NODES*4);
  int*   offs = (int*)carve((size_t)(N_NODES+1)*4);
  int*   head = (int*)carve((size_t)N_NODES*4);
  int*   eidx = (int*)carve((size_t)E_EDGES*4);
  UST*   e1   = (UST*)carve((size_t)E_EDGES*256*2);
  UST*   yA   = (UST*)carve((size_t)M_PAD*512*2);
  UST*   t1   = (UST*)carve((size_t)M_PAD*256*2);

  hipMemsetAsync(cnti, 0, (size_t)N_NODES*4, stream);

  prep_w<<<928, 256, 0, stream>>>(We1, We2, Wn1, Wn2, W1T, W2T, Wn1T, Wn2T);
  ln_kernel<<<N_NODES/4, 256, 0, stream>>>(node_features, ln_gamma, ln_beta, hbf);
  ltl_kernel<<<36, 256, 0, stream>>>(lattices, ltl);

  cnt_kernel<<<E_EDGES/256, 256, 0, stream>>>(edge_index, cnti);
  scan_kernel<<<1, 256, 0, stream>>>(cnti, offs, head);
  fill_kernel<<<E_EDGES/256, 256, 0, stream>>>(edge_index, head, eidx);

  gemm_edge1<<<E_EDGES/128, 512, 0, stream>>>(
      hbf, edge_index, edge2graph, frac_diff, ltl, W1T, be1, e1);

  // edge MLP2, in-place over e1 (each block reads only its own rows)
  gemm_bt<0><<<E_EDGES/128, 512, 0, stream>>>(
      e1, W2T, be2, 256, e1, nullptr, nullptr, 0);

  agg_kernel<<<M_PAD, 256, 0, stream>>>(e1, offs, eidx, hbf, yA);

  gemm_bt<0><<<M_PAD/128, 512, 0, stream>>>(
      yA, Wn1T, bn1, 512, t1, nullptr, nullptr, 0);

  gemm_bt<2><<<M_PAD/128, 512, 0, stream>>>(
      t1, Wn2T, bn2, 256, nullptr, (float*)d_out, node_features, N_NODES);
}

// Round 4
// 542.717 us; speedup vs baseline: 1.3425x; 1.1082x over previous
//
#include <hip/hip_runtime.h>

typedef unsigned short UST;
typedef __bf16 bf16x8 __attribute__((ext_vector_type(8)));
typedef float floatx4 __attribute__((ext_vector_type(4)));
typedef unsigned short ushort8v __attribute__((ext_vector_type(8)));
typedef unsigned short ushort4v __attribute__((ext_vector_type(4)));

#define N_NODES 20000
#define E_EDGES 320000
#define KE 928         // padded edge-MLP K: [hi 0:256 | hj 256:512 | fd(interleaved sin/cos) 512:896 | le 896:905 | pad:928]
#define M_PAD 20096    // 157*128

static __device__ __forceinline__ UST f2bf(float x){
  unsigned int u = __float_as_uint(x);
  u += 0x7fffu + ((u >> 16) & 1u);   // round-to-nearest-even
  return (UST)(u >> 16);
}
static __device__ __forceinline__ float bf2f(UST u){
  return __uint_as_float(((unsigned int)u) << 16);
}
static __device__ __forceinline__ float siluf(float v){
  return v / (1.0f + __expf(-v));
}
// async global->LDS, 16B per lane; LDS dest must be wave-uniform base + lane*16
static __device__ __forceinline__ void gll16(const void* g, void* lds){
  __builtin_amdgcn_global_load_lds(
      (const __attribute__((address_space(1))) unsigned int*)g,
      (__attribute__((address_space(3))) unsigned int*)lds, 16, 0, 0);
}

// As: 128 rows x 32 cols (64B stride). Bs: 256 rows x 32 cols. Wave: 64x64 at (wM,wN).
static __device__ __forceinline__ void mfma_step(const UST* As, const UST* Bs,
    floatx4 (&acc)[4][4], int lm, int quad, int wM, int wN){
  bf16x8 a[4], b[4];
#pragma unroll
  for (int i = 0; i < 4; ++i)
    a[i] = *(const bf16x8*)(As + (wM + i*16 + lm)*32 + quad*8);
#pragma unroll
  for (int i = 0; i < 4; ++i)
    b[i] = *(const bf16x8*)(Bs + (wN + i*16 + lm)*32 + quad*8);
#pragma unroll
  for (int mi = 0; mi < 4; ++mi)
#pragma unroll
    for (int ni = 0; ni < 4; ++ni)
      acc[mi][ni] = __builtin_amdgcn_mfma_f32_16x16x32_bf16(a[mi], b[ni], acc[mi][ni], 0, 0, 0);
}

// ---------------- LayerNorm: one wave per row, h -> bf16 ----------------
__global__ __launch_bounds__(256) void ln_kernel(const float* __restrict__ x,
    const float* __restrict__ gamma, const float* __restrict__ beta,
    UST* __restrict__ h){
  int wave = threadIdx.x >> 6, lane = threadIdx.x & 63;
  int row = blockIdx.x * 4 + wave;
  const float4* xp = (const float4*)(x + (size_t)row * 256);
  float4 v = xp[lane];
  float s  = v.x + v.y + v.z + v.w;
  float sq = v.x*v.x + v.y*v.y + v.z*v.z + v.w*v.w;
#pragma unroll
  for (int o = 32; o > 0; o >>= 1){ s += __shfl_xor(s, o); sq += __shfl_xor(sq, o); }
  float mu  = s * (1.0f/256.0f);
  float var = sq * (1.0f/256.0f) - mu*mu;
  float rs  = rsqrtf(var + 1e-5f);
  float4 g = ((const float4*)gamma)[lane];
  float4 b = ((const float4*)beta)[lane];
  ushort4v o4;
  o4[0] = f2bf((v.x-mu)*rs*g.x + b.x);
  o4[1] = f2bf((v.y-mu)*rs*g.y + b.y);
  o4[2] = f2bf((v.z-mu)*rs*g.z + b.z);
  o4[3] = f2bf((v.w-mu)*rs*g.w + b.w);
  *(ushort4v*)(h + (size_t)row*256 + lane*4) = o4;
}

// ---------------- ltl = L @ L^T per graph ----------------
__global__ __launch_bounds__(256) void ltl_kernel(const float* __restrict__ lat,
                                                  float* __restrict__ ltl){
  int i = blockIdx.x*256 + threadIdx.x;
  if (i >= 9000) return;
  int g = i / 9, ij = i % 9, a = ij / 3, b = ij % 3;
  const float* L = lat + g*9;
  ltl[i] = L[a*3+0]*L[b*3+0] + L[a*3+1]*L[b*3+1] + L[a*3+2]*L[b*3+2];
}

// ---------------- weight prep: transpose -> bf16 ----------------
// W1T row map: [0:512)=hi|hj, [512:896)=fd interleaved (col 512+2j+b -> orig 521+b*192+j),
// [896:905)=le (orig 512..520), [905:928)=0
__global__ __launch_bounds__(256) void prep_w(const float* __restrict__ We1,
    const float* __restrict__ We2, const float* __restrict__ Wn1,
    const float* __restrict__ Wn2, UST* __restrict__ W1T, UST* __restrict__ W2T,
    UST* __restrict__ Wn1T, UST* __restrict__ Wn2T){
  int i = blockIdx.x*256 + threadIdx.x;
  if (i < 256*KE){
    int n = i / KE, k = i % KE;
    float v = 0.0f;
    if (k < 512)      v = We1[(size_t)k*256 + n];
    else if (k < 896){
      int idx = k - 512, j = idx >> 1, b = idx & 1;
      v = We1[(size_t)(521 + b*192 + j)*256 + n];
    }
    else if (k < 905) v = We1[(size_t)(k-384)*256 + n];
    W1T[i] = f2bf(v);
  }
  if (i < 256*256){
    int n = i >> 8, k = i & 255;
    W2T[i]  = f2bf(We2[(size_t)k*256 + n]);
    Wn2T[i] = f2bf(Wn2[(size_t)k*256 + n]);
  }
  if (i < 256*512){
    int n = i >> 9, k = i & 511;
    Wn1T[i] = f2bf(Wn1[(size_t)k*256 + n]);
  }
}

// ---------------- CSR build: histogram -> scan -> fill (+sorted srcs) ----------------
__global__ __launch_bounds__(256) void cnt_kernel(const int* __restrict__ src,
                                                  int* __restrict__ cnti){
  int e = blockIdx.x*256 + threadIdx.x;
  if (e < E_EDGES) atomicAdd(&cnti[src[e]], 1);
}

__global__ __launch_bounds__(256) void scan_kernel(const int* __restrict__ cnti,
    int* __restrict__ off, int* __restrict__ head){
  __shared__ int ps[256];
  int t = threadIdx.x;
  const int CH = 80;                       // 256*80 = 20480 >= 20000 (cnti padded)
  const int4* cp = (const int4*)cnti;
  int base = t * CH;
  int s = 0;
#pragma unroll 1
  for (int i = 0; i < CH/4; ++i){
    int4 v = cp[t*(CH/4) + i];
    int idx = base + i*4;
    if (idx   < N_NODES) s += v.x;
    if (idx+1 < N_NODES) s += v.y;
    if (idx+2 < N_NODES) s += v.z;
    if (idx+3 < N_NODES) s += v.w;
  }
  ps[t] = s; __syncthreads();
#pragma unroll 1
  for (int o = 1; o < 256; o <<= 1){
    int v = (t >= o) ? ps[t - o] : 0;
    __syncthreads();
    ps[t] += v;
    __syncthreads();
  }
  int run = (t > 0) ? ps[t-1] : 0;
#pragma unroll 1
  for (int i = 0; i < CH/4; ++i){
    int4 v = cp[t*(CH/4) + i];
    int idx = base + i*4;
    int a4[4] = {v.x, v.y, v.z, v.w};
#pragma unroll
    for (int j = 0; j < 4; ++j){
      int id = idx + j;
      if (id < N_NODES){ off[id] = run; head[id] = run; run += a4[j]; }
    }
  }
  if (t == 255) off[N_NODES] = run;
}

__global__ __launch_bounds__(256) void fill_kernel(const int* __restrict__ src,
    int* __restrict__ head, int* __restrict__ eidx, int* __restrict__ srcs){
  int e = blockIdx.x*256 + threadIdx.x;
  if (e < E_EDGES){
    int s = src[e];
    int p = atomicAdd(&head[s], 1);
    eidx[p] = e;
    srcs[p] = s;
  }
}

// ---------------- GEMM1: fused x-construction, rows in CSR-permuted order ----------------
// 512 threads, 128x256 tile, BK=64 (split As0/As1, Bs0/Bs1), 32 MFMA per barrier-pair
__global__ __launch_bounds__(512)
void gemm_edge1(const UST* __restrict__ h, const int* __restrict__ ei,
                const int* __restrict__ e2g, const float* __restrict__ fdif,
                const float* __restrict__ ltl, const UST* __restrict__ W1T,
                const float* __restrict__ be1, const int* __restrict__ eidx,
                UST* __restrict__ e1){
  __shared__ __attribute__((aligned(16))) UST As0[128*32];
  __shared__ __attribute__((aligned(16))) UST As1[128*32];
  __shared__ __attribute__((aligned(16))) UST Bs0[256*32];
  __shared__ __attribute__((aligned(16))) UST Bs1[256*32];
  int t = threadIdx.x;
  int bM = blockIdx.x;
  int rA = t >> 2, cA = (t & 3) * 8;       // one A-row per thread, 8-ushort chunk
  int p0 = bM*128 + rA;
  int e0 = eidx[p0];
  int src0 = ei[e0];
  int dst0 = ei[E_EDGES + e0];
  int g0 = e2g[e0];
  float f0x = fdif[e0*3+0], f0y = fdif[e0*3+1], f0z = fdif[e0*3+2];
  size_t btb0 = (size_t)rA*KE + cA;        // B rows rA, rA+128
  size_t btb1 = btb0 + (size_t)128*KE;
  int lane = t & 63, lm = lane & 15, quad = lane >> 4;
  int wave = t >> 6, wM = (wave >> 2)*64, wN = (wave & 3)*64;
  floatx4 acc[4][4] = {};
  UST* a0d = &As0[rA*32 + cA];
  UST* a1d = &As1[rA*32 + cA];
  UST* b0d0 = &Bs0[rA*32 + cA];
  UST* b0d1 = &Bs0[(128+rA)*32 + cA];
  UST* b1d0 = &Bs1[rA*32 + cA];
  UST* b1d1 = &Bs1[(128+rA)*32 + cA];

#pragma unroll 1
  for (int w = 0; w < 8; ++w){            // hi (w<4) then hj (w>=4)
    int k0 = w*64;
    const UST* srow = (w < 4) ? (h + (size_t)src0*256 + k0)
                              : (h + (size_t)dst0*256 + (k0 - 256));
    gll16(srow + cA,      a0d);
    gll16(srow + 32 + cA, a1d);
    gll16(W1T + btb0 + k0,      b0d0);
    gll16(W1T + btb1 + k0,      b0d1);
    gll16(W1T + btb0 + k0 + 32, b1d0);
    gll16(W1T + btb1 + k0 + 32, b1d1);
    __syncthreads();
    mfma_step(As0, Bs0, acc, lm, quad, wM, wN);
    mfma_step(As1, Bs1, acc, lm, quad, wM, wN);
    __syncthreads();
  }
#pragma unroll 1
  for (int w = 8; w < 14; ++w){           // fd: interleaved sin/cos pairs
    int k0 = w*64;
    int jb0 = (k0 + cA - 512) >> 1;       // 4 angles per half-window
    ushort8v o0, o1;
#pragma unroll
    for (int ii = 0; ii < 4; ++ii){
      int jj = jb0 + ii;
      int dim = jj >> 6; float kf = (float)(jj & 63);
      float fr = (dim == 0) ? f0x : ((dim == 1) ? f0y : f0z);
      float q = __builtin_amdgcn_fractf(fr * kf);
      o0[2*ii]   = f2bf(__builtin_amdgcn_sinf(q));
      o0[2*ii+1] = f2bf(__builtin_amdgcn_cosf(q));
    }
#pragma unroll
    for (int ii = 0; ii < 4; ++ii){
      int jj = jb0 + 16 + ii;
      int dim = jj >> 6; float kf = (float)(jj & 63);
      float fr = (dim == 0) ? f0x : ((dim == 1) ? f0y : f0z);
      float q = __builtin_amdgcn_fractf(fr * kf);
      o1[2*ii]   = f2bf(__builtin_amdgcn_sinf(q));
      o1[2*ii+1] = f2bf(__builtin_amdgcn_cosf(q));
    }
    *(ushort8v*)a0d = o0;
    *(ushort8v*)a1d = o1;
    gll16(W1T + btb0 + k0,      b0d0);
    gll16(W1T + btb1 + k0,      b0d1);
    gll16(W1T + btb0 + k0 + 32, b1d0);
    gll16(W1T + btb1 + k0 + 32, b1d1);
    __syncthreads();
    mfma_step(As0, Bs0, acc, lm, quad, wM, wN);
    mfma_step(As1, Bs1, acc, lm, quad, wM, wN);
    __syncthreads();
  }
  {                                       // half window k0=896: le + pad (As0/Bs0 only)
    ushort8v o0;
#pragma unroll
    for (int i = 0; i < 8; ++i){
      int c = cA + i;
      o0[i] = (c < 9) ? f2bf(ltl[g0*9 + c]) : (UST)0;
    }
    *(ushort8v*)a0d = o0;
    gll16(W1T + btb0 + 896, b0d0);
    gll16(W1T + btb1 + 896, b0d1);
    __syncthreads();
    mfma_step(As0, Bs0, acc, lm, quad, wM, wN);
  }
  // epilogue: + be1, silu, bf16 store (C/D: row=quad*4+reg, col=lane&15)
  int mbase = bM*128 + wM + quad*4;
  int nbase = wN + lm;
#pragma unroll
  for (int mi = 0; mi < 4; ++mi)
#pragma unroll
    for (int r = 0; r < 4; ++r){
      int m = mbase + mi*16 + r;
#pragma unroll
      for (int ni = 0; ni < 4; ++ni){
        int n = nbase + ni*16;
        float v = acc[mi][ni][r] + be1[n];
        e1[(size_t)m*256 + n] = f2bf(siluf(v));
      }
    }
}

// ---------------- fused edge-MLP2 + segmented scatter-mean-sum ----------------
// A = e1 (CSR-permuted rows), B = W2T, K=256. Epilogue: silu -> EsT (col-major LDS)
// -> per-column segmented sum over the 128 rows -> fp32 atomicAdd per (segment,col).
__global__ __launch_bounds__(512)
void gemm_mlp2agg(const UST* __restrict__ A, const UST* __restrict__ B,
                  const float* __restrict__ bias, const int* __restrict__ rownode,
                  float* __restrict__ sums){
  __shared__ __attribute__((aligned(16))) UST lds[256*132];  // 67.6KB union
  __shared__ int rn[128];
  UST* As0 = lds;            // 128*32
  UST* As1 = lds + 4096;
  UST* Bs0 = lds + 8192;     // 256*32
  UST* Bs1 = lds + 16384;
  UST* EsT = lds;            // [256 cols][132 rows pad]
  int t = threadIdx.x;
  int bM = blockIdx.x;
  int rA = t >> 2, cA = (t & 3) * 8;
  size_t ab  = (size_t)(bM*128 + rA)*256 + cA;
  size_t bb0 = (size_t)rA*256 + cA;
  size_t bb1 = bb0 + (size_t)128*256;
  int lane = t & 63, lm = lane & 15, quad = lane >> 4;
  int wave = t >> 6, wM = (wave >> 2)*64, wN = (wave & 3)*64;
  floatx4 acc[4][4] = {};
  UST* a0d = &As0[rA*32 + cA];
  UST* a1d = &As1[rA*32 + cA];
  UST* b0d0 = &Bs0[rA*32 + cA];
  UST* b0d1 = &Bs0[(128+rA)*32 + cA];
  UST* b1d0 = &Bs1[rA*32 + cA];
  UST* b1d1 = &Bs1[(128+rA)*32 + cA];
#pragma unroll 1
  for (int k0 = 0; k0 < 256; k0 += 64){
    gll16(A + ab + k0,       a0d);
    gll16(A + ab + k0 + 32,  a1d);
    gll16(B + bb0 + k0,      b0d0);
    gll16(B + bb1 + k0,      b0d1);
    gll16(B + bb0 + k0 + 32, b1d0);
    gll16(B + bb1 + k0 + 32, b1d1);
    __syncthreads();
    mfma_step(As0, Bs0, acc, lm, quad, wM, wN);
    mfma_step(As1, Bs1, acc, lm, quad, wM, wN);
    __syncthreads();
  }
  // silu + transpose-store to EsT (ushort4 = 4 consecutive rows, one col)
#pragma unroll
  for (int mi = 0; mi < 4; ++mi)
#pragma unroll
    for (int ni = 0; ni < 4; ++ni){
      int nl = wN + ni*16 + lm;
      int ml = wM + mi*16 + quad*4;
      ushort4v pk;
#pragma unroll
      for (int r = 0; r < 4; ++r)
        pk[r] = f2bf(siluf(acc[mi][ni][r] + bias[nl]));
      *(ushort4v*)&EsT[nl*132 + ml] = pk;
    }
  if (t < 128) rn[t] = rownode[bM*128 + t];
  __syncthreads();
  // segmented column sums (256 threads, one col each)
  if (t < 256){
    int c = t;
    int cur = rn[0];
    float run = 0.0f;
#pragma unroll 1
    for (int r = 0; r < 128; r += 4){
      ushort4v v4 = *(const ushort4v*)&EsT[c*132 + r];
#pragma unroll
      for (int q2 = 0; q2 < 4; ++q2){
        int nd = rn[r + q2];
        if (nd != cur){ atomicAdd(&sums[(size_t)cur*256 + c], run); run = 0.0f; cur = nd; }
        run += bf2f(v4[q2]);
      }
    }
    atomicAdd(&sums[(size_t)cur*256 + c], run);
  }
}

// ---------------- generic bf16 GEMM, BK=64, 512 thr, 128x256 tile ----------------
// MODE 0: silu(+bias) -> bf16 store. MODE 2: silu(+bias)+resid -> fp32 if m<mlimit.
template<int MODE>
__global__ __launch_bounds__(512)
void gemm_bt(const UST* __restrict__ A, const UST* __restrict__ B,
             const float* __restrict__ bias, int K,
             UST* __restrict__ out_bf, float* __restrict__ out_f,
             const float* __restrict__ resid, int mlimit){
  __shared__ __attribute__((aligned(16))) UST As0[128*32];
  __shared__ __attribute__((aligned(16))) UST As1[128*32];
  __shared__ __attribute__((aligned(16))) UST Bs0[256*32];
  __shared__ __attribute__((aligned(16))) UST Bs1[256*32];
  int t = threadIdx.x;
  int bM = blockIdx.x;
  int rA = t >> 2, cA = (t & 3) * 8;
  size_t ab  = (size_t)(bM*128 + rA)*K + cA;
  size_t bb0 = (size_t)rA*K + cA;
  size_t bb1 = bb0 + (size_t)128*K;
  int lane = t & 63, lm = lane & 15, quad = lane >> 4;
  int wave = t >> 6, wM = (wave >> 2)*64, wN = (wave & 3)*64;
  floatx4 acc[4][4] = {};
  UST* a0d = &As0[rA*32 + cA];
  UST* a1d = &As1[rA*32 + cA];
  UST* b0d0 = &Bs0[rA*32 + cA];
  UST* b0d1 = &Bs0[(128+rA)*32 + cA];
  UST* b1d0 = &Bs1[rA*32 + cA];
  UST* b1d1 = &Bs1[(128+rA)*32 + cA];
#pragma unroll 1
  for (int k0 = 0; k0 < K; k0 += 64){
    gll16(A + ab + k0,       a0d);
    gll16(A + ab + k0 + 32,  a1d);
    gll16(B + bb0 + k0,      b0d0);
    gll16(B + bb1 + k0,      b0d1);
    gll16(B + bb0 + k0 + 32, b1d0);
    gll16(B + bb1 + k0 + 32, b1d1);
    __syncthreads();
    mfma_step(As0, Bs0, acc, lm, quad, wM, wN);
    mfma_step(As1, Bs1, acc, lm, quad, wM, wN);
    __syncthreads();
  }
  int mbase = bM*128 + wM + quad*4;
  int nbase = wN + lm;
#pragma unroll
  for (int mi = 0; mi < 4; ++mi)
#pragma unroll
    for (int r = 0; r < 4; ++r){
      int m = mbase + mi*16 + r;
#pragma unroll
      for (int ni = 0; ni < 4; ++ni){
        int n = nbase + ni*16;
        float v = acc[mi][ni][r] + bias[n];
        v = siluf(v);
        if (MODE == 0){
          out_bf[(size_t)m*256 + n] = f2bf(v);
        } else {
          if (m < mlimit) out_f[(size_t)m*256 + n] = resid[(size_t)m*256 + n] + v;
        }
      }
    }
}

// ---------------- build yA = [h | sums/deg] bf16, rows padded to M_PAD ----------------
__global__ __launch_bounds__(256) void build_yA(const UST* __restrict__ h,
    const float* __restrict__ sums, const int* __restrict__ offs,
    UST* __restrict__ yA){
  int i = blockIdx.x*256 + threadIdx.x;
  int row = i >> 7, q = i & 127;
  ushort4v v = {0, 0, 0, 0};
  if (row < N_NODES){
    if (q < 64){
      v = *(const ushort4v*)(h + (size_t)row*256 + q*4);
    } else {
      int deg = offs[row+1] - offs[row];
      float inv = 1.0f / fmaxf((float)deg, 1.0f);
      float4 s = ((const float4*)(sums + (size_t)row*256))[q - 64];
      v[0] = f2bf(s.x*inv); v[1] = f2bf(s.y*inv);
      v[2] = f2bf(s.z*inv); v[3] = f2bf(s.w*inv);
    }
  }
  *(ushort4v*)(yA + (size_t)row*512 + q*4) = v;
}

extern "C" void kernel_launch(void* const* d_in, const int* in_sizes, int n_in,
                              void* d_out, int out_size, void* d_ws, size_t ws_size,
                              hipStream_t stream){
  (void)in_sizes; (void)n_in; (void)out_size; (void)ws_size;
  const float* node_features = (const float*)d_in[0];
  const float* lattices      = (const float*)d_in[1];
  const int*   edge_index    = (const int*)d_in[2];   // [2,E]: row0=src, row1=dst
  const int*   edge2graph    = (const int*)d_in[3];
  const float* frac_diff     = (const float*)d_in[4];
  const float* ln_gamma      = (const float*)d_in[6];
  const float* ln_beta       = (const float*)d_in[7];
  const float* We1 = (const float*)d_in[8];
  const float* be1 = (const float*)d_in[9];
  const float* We2 = (const float*)d_in[10];
  const float* be2 = (const float*)d_in[11];
  const float* Wn1 = (const float*)d_in[12];
  const float* bn1 = (const float*)d_in[13];
  const float* Wn2 = (const float*)d_in[14];
  const float* bn2 = (const float*)d_in[15];

  char* w = (char*)d_ws;
  size_t off_b = 0;
  auto carve = [&](size_t bytes) -> char* {
    char* p = w + off_b; off_b += (bytes + 1023) & ~(size_t)1023; return p;
  };
  UST*   W1T  = (UST*)carve((size_t)256*KE*2);
  UST*   W2T  = (UST*)carve((size_t)256*256*2);
  UST*   Wn1T = (UST*)carve((size_t)256*512*2);
  UST*   Wn2T = (UST*)carve((size_t)256*256*2);
  UST*   hbf  = (UST*)carve((size_t)N_NODES*256*2);
  float* ltl  = (float*)carve((size_t)9000*4);
  int*   cnti = (int*)carve((size_t)20480*4);          // padded for int4 scan
  int*   offs = (int*)carve((size_t)(N_NODES+1)*4);
  int*   head = (int*)carve((size_t)N_NODES*4);
  int*   eidx = (int*)carve((size_t)E_EDGES*4);
  int*   srcs = (int*)carve((size_t)E_EDGES*4);        // sorted src per CSR slot
  float* sums = (float*)carve((size_t)N_NODES*256*4);
  UST*   e1   = (UST*)carve((size_t)E_EDGES*256*2);
  UST*   yA   = (UST*)carve((size_t)M_PAD*512*2);
  UST*   t1   = (UST*)carve((size_t)M_PAD*256*2);

  hipMemsetAsync(cnti, 0, (size_t)20480*4, stream);
  hipMemsetAsync(sums, 0, (size_t)N_NODES*256*4, stream);

  prep_w<<<928, 256, 0, stream>>>(We1, We2, Wn1, Wn2, W1T, W2T, Wn1T, Wn2T);
  ln_kernel<<<N_NODES/4, 256, 0, stream>>>(node_features, ln_gamma, ln_beta, hbf);
  ltl_kernel<<<36, 256, 0, stream>>>(lattices, ltl);

  cnt_kernel<<<E_EDGES/256, 256, 0, stream>>>(edge_index, cnti);
  scan_kernel<<<1, 256, 0, stream>>>(cnti, offs, head);
  fill_kernel<<<E_EDGES/256, 256, 0, stream>>>(edge_index, head, eidx, srcs);

  gemm_edge1<<<E_EDGES/128, 512, 0, stream>>>(
      hbf, edge_index, edge2graph, frac_diff, ltl, W1T, be1, eidx, e1);

  gemm_mlp2agg<<<E_EDGES/128, 512, 0, stream>>>(e1, W2T, be2, srcs, sums);

  build_yA<<<(M_PAD*128)/256, 256, 0, stream>>>(hbf, sums, offs, yA);

  gemm_bt<0><<<M_PAD/128, 512, 0, stream>>>(
      yA, Wn1T, bn1, 512, t1, nullptr, nullptr, 0);

  gemm_bt<2><<<M_PAD/128, 512, 0, stream>>>(
      t1, Wn2T, bn2, 256, nullptr, (float*)d_out, node_features, N_NODES);
}

// Round 5
// 522.618 us; speedup vs baseline: 1.3942x; 1.0385x over previous
//
#include <hip/hip_runtime.h>

typedef unsigned short UST;
typedef __bf16 bf16x8 __attribute__((ext_vector_type(8)));
typedef float floatx4 __attribute__((ext_vector_type(4)));
typedef unsigned short ushort8v __attribute__((ext_vector_type(8)));
typedef unsigned short ushort4v __attribute__((ext_vector_type(4)));

#define N_NODES 20000
#define E_EDGES 320000
#define KE 928         // padded edge-MLP K: [hi 0:256 | hj 256:512 | fd(interleaved sin/cos) 512:896 | le 896:905 | pad:928]
#define M_PAD 20096    // 157*128

static __device__ __forceinline__ UST f2bf(float x){
  unsigned int u = __float_as_uint(x);
  u += 0x7fffu + ((u >> 16) & 1u);   // round-to-nearest-even
  return (UST)(u >> 16);
}
static __device__ __forceinline__ float bf2f(UST u){
  return __uint_as_float(((unsigned int)u) << 16);
}
static __device__ __forceinline__ float siluf(float v){
  return v / (1.0f + __expf(-v));
}
// async global->LDS, 16B per lane; LDS dest must be wave-uniform base + lane*16
static __device__ __forceinline__ void gll16(const void* g, void* lds){
  __builtin_amdgcn_global_load_lds(
      (const __attribute__((address_space(1))) unsigned int*)g,
      (__attribute__((address_space(3))) unsigned int*)lds, 16, 0, 0);
}

// As: 128 rows x 32 cols (64B stride). Bs: 256 rows x 32 cols. Wave: 64x64 at (wM,wN).
static __device__ __forceinline__ void mfma_step(const UST* As, const UST* Bs,
    floatx4 (&acc)[4][4], int lm, int quad, int wM, int wN){
  bf16x8 a[4], b[4];
#pragma unroll
  for (int i = 0; i < 4; ++i)
    a[i] = *(const bf16x8*)(As + (wM + i*16 + lm)*32 + quad*8);
#pragma unroll
  for (int i = 0; i < 4; ++i)
    b[i] = *(const bf16x8*)(Bs + (wN + i*16 + lm)*32 + quad*8);
#pragma unroll
  for (int mi = 0; mi < 4; ++mi)
#pragma unroll
    for (int ni = 0; ni < 4; ++ni)
      acc[mi][ni] = __builtin_amdgcn_mfma_f32_16x16x32_bf16(a[mi], b[ni], acc[mi][ni], 0, 0, 0);
}

// ---------------- LayerNorm: one wave per row, h -> bf16 ----------------
__global__ __launch_bounds__(256) void ln_kernel(const float* __restrict__ x,
    const float* __restrict__ gamma, const float* __restrict__ beta,
    UST* __restrict__ h){
  int wave = threadIdx.x >> 6, lane = threadIdx.x & 63;
  int row = blockIdx.x * 4 + wave;
  const float4* xp = (const float4*)(x + (size_t)row * 256);
  float4 v = xp[lane];
  float s  = v.x + v.y + v.z + v.w;
  float sq = v.x*v.x + v.y*v.y + v.z*v.z + v.w*v.w;
#pragma unroll
  for (int o = 32; o > 0; o >>= 1){ s += __shfl_xor(s, o); sq += __shfl_xor(sq, o); }
  float mu  = s * (1.0f/256.0f);
  float var = sq * (1.0f/256.0f) - mu*mu;
  float rs  = rsqrtf(var + 1e-5f);
  float4 g = ((const float4*)gamma)[lane];
  float4 b = ((const float4*)beta)[lane];
  ushort4v o4;
  o4[0] = f2bf((v.x-mu)*rs*g.x + b.x);
  o4[1] = f2bf((v.y-mu)*rs*g.y + b.y);
  o4[2] = f2bf((v.z-mu)*rs*g.z + b.z);
  o4[3] = f2bf((v.w-mu)*rs*g.w + b.w);
  *(ushort4v*)(h + (size_t)row*256 + lane*4) = o4;
}

// ---------------- ltl = L @ L^T per graph ----------------
__global__ __launch_bounds__(256) void ltl_kernel(const float* __restrict__ lat,
                                                  float* __restrict__ ltl){
  int i = blockIdx.x*256 + threadIdx.x;
  if (i >= 9000) return;
  int g = i / 9, ij = i % 9, a = ij / 3, b = ij % 3;
  const float* L = lat + g*9;
  ltl[i] = L[a*3+0]*L[b*3+0] + L[a*3+1]*L[b*3+1] + L[a*3+2]*L[b*3+2];
}

// ---------------- weight prep: transpose -> bf16 ----------------
// W1T row map: [0:512)=hi|hj, [512:896)=fd interleaved (col 512+2j+b -> orig 521+b*192+j),
// [896:905)=le (orig 512..520), [905:928)=0
__global__ __launch_bounds__(256) void prep_w(const float* __restrict__ We1,
    const float* __restrict__ We2, const float* __restrict__ Wn1,
    const float* __restrict__ Wn2, UST* __restrict__ W1T, UST* __restrict__ W2T,
    UST* __restrict__ Wn1T, UST* __restrict__ Wn2T){
  int i = blockIdx.x*256 + threadIdx.x;
  if (i < 256*KE){
    int n = i / KE, k = i % KE;
    float v = 0.0f;
    if (k < 512)      v = We1[(size_t)k*256 + n];
    else if (k < 896){
      int idx = k - 512, j = idx >> 1, b = idx & 1;
      v = We1[(size_t)(521 + b*192 + j)*256 + n];
    }
    else if (k < 905) v = We1[(size_t)(k-384)*256 + n];
    W1T[i] = f2bf(v);
  }
  if (i < 256*256){
    int n = i >> 8, k = i & 255;
    W2T[i]  = f2bf(We2[(size_t)k*256 + n]);
    Wn2T[i] = f2bf(Wn2[(size_t)k*256 + n]);
  }
  if (i < 256*512){
    int n = i >> 9, k = i & 511;
    Wn1T[i] = f2bf(Wn1[(size_t)k*256 + n]);
  }
}

// ---------------- CSR build: histogram -> scan -> fill (+sorted srcs) ----------------
__global__ __launch_bounds__(256) void cnt_kernel(const int* __restrict__ src,
                                                  int* __restrict__ cnti){
  int e = blockIdx.x*256 + threadIdx.x;
  if (e < E_EDGES) atomicAdd(&cnti[src[e]], 1);
}

__global__ __launch_bounds__(256) void scan_kernel(const int* __restrict__ cnti,
    int* __restrict__ off, int* __restrict__ head){
  __shared__ int ps[256];
  int t = threadIdx.x;
  const int CH = 80;                       // 256*80 = 20480 >= 20000 (cnti padded)
  const int4* cp = (const int4*)cnti;
  int base = t * CH;
  int s = 0;
#pragma unroll 1
  for (int i = 0; i < CH/4; ++i){
    int4 v = cp[t*(CH/4) + i];
    int idx = base + i*4;
    if (idx   < N_NODES) s += v.x;
    if (idx+1 < N_NODES) s += v.y;
    if (idx+2 < N_NODES) s += v.z;
    if (idx+3 < N_NODES) s += v.w;
  }
  ps[t] = s; __syncthreads();
#pragma unroll 1
  for (int o = 1; o < 256; o <<= 1){
    int v = (t >= o) ? ps[t - o] : 0;
    __syncthreads();
    ps[t] += v;
    __syncthreads();
  }
  int run = (t > 0) ? ps[t-1] : 0;
#pragma unroll 1
  for (int i = 0; i < CH/4; ++i){
    int4 v = cp[t*(CH/4) + i];
    int idx = base + i*4;
    int a4[4] = {v.x, v.y, v.z, v.w};
#pragma unroll
    for (int j = 0; j < 4; ++j){
      int id = idx + j;
      if (id < N_NODES){ off[id] = run; head[id] = run; run += a4[j]; }
    }
  }
  if (t == 255) off[N_NODES] = run;
}

__global__ __launch_bounds__(256) void fill_kernel(const int* __restrict__ src,
    int* __restrict__ head, int* __restrict__ eidx, int* __restrict__ srcs){
  int e = blockIdx.x*256 + threadIdx.x;
  if (e < E_EDGES){
    int s = src[e];
    int p = atomicAdd(&head[s], 1);
    eidx[p] = e;
    srcs[p] = s;
  }
}

// ======== MEGA-KERNEL: edge MLP1 (fused x-construction) + MLP2 + seg-scatter ========
// Phase 1: e1 = silu(x @ We1 + be1), stores its own 128x256 tile to e1 (global scratch).
// Phase 2: reads the tile back (L2-hot, same CU just wrote it, syncthreads drains vmcnt),
//          e2 = silu(e1 @ We2 + be2), K=256.
// Phase 3: transpose via LDS, segmented sum over CSR-ordered rows, atomicAdd into sums.
__global__ __launch_bounds__(512)
void gemm_edge_fused(const UST* __restrict__ h, const int* __restrict__ ei,
                     const int* __restrict__ e2g, const float* __restrict__ fdif,
                     const float* __restrict__ ltl, const UST* __restrict__ W1T,
                     const float* __restrict__ be1, const int* __restrict__ eidx,
                     const UST* __restrict__ W2T, const float* __restrict__ be2,
                     const int* __restrict__ rownode,
                     UST* __restrict__ e1, float* __restrict__ sums){
  __shared__ __attribute__((aligned(16))) UST lds[256*132];  // 67.6KB union
  __shared__ int rn[128];
  UST* As0 = lds;             // 128*32
  UST* As1 = lds + 4096;
  UST* Bs0 = lds + 8192;      // 256*32
  UST* Bs1 = lds + 16384;
  UST* EsT = lds;             // [256 cols][132 rows pad]
  int t = threadIdx.x;
  int bM = blockIdx.x;
  int rA = t >> 2, cA = (t & 3) * 8;       // one A-row per thread, 8-ushort chunk
  int p0 = bM*128 + rA;
  int e0 = eidx[p0];
  int src0 = ei[e0];
  int dst0 = ei[E_EDGES + e0];
  int g0 = e2g[e0];
  float f0x = fdif[e0*3+0], f0y = fdif[e0*3+1], f0z = fdif[e0*3+2];
  size_t btb0 = (size_t)rA*KE + cA;        // W1T rows rA, rA+128
  size_t btb1 = btb0 + (size_t)128*KE;
  int lane = t & 63, lm = lane & 15, quad = lane >> 4;
  int wave = t >> 6, wM = (wave >> 2)*64, wN = (wave & 3)*64;
  floatx4 acc[4][4] = {};
  UST* a0d = &As0[rA*32 + cA];
  UST* a1d = &As1[rA*32 + cA];
  UST* b0d0 = &Bs0[rA*32 + cA];
  UST* b0d1 = &Bs0[(128+rA)*32 + cA];
  UST* b1d0 = &Bs1[rA*32 + cA];
  UST* b1d1 = &Bs1[(128+rA)*32 + cA];
  if (t < 128) rn[t] = rownode[bM*128 + t];

  // ---- phase 1: K-loop over KE ----
#pragma unroll 1
  for (int w = 0; w < 8; ++w){            // hi (w<4) then hj (w>=4)
    int k0 = w*64;
    const UST* srow = (w < 4) ? (h + (size_t)src0*256 + k0)
                              : (h + (size_t)dst0*256 + (k0 - 256));
    gll16(srow + cA,      a0d);
    gll16(srow + 32 + cA, a1d);
    gll16(W1T + btb0 + k0,      b0d0);
    gll16(W1T + btb1 + k0,      b0d1);
    gll16(W1T + btb0 + k0 + 32, b1d0);
    gll16(W1T + btb1 + k0 + 32, b1d1);
    __syncthreads();
    mfma_step(As0, Bs0, acc, lm, quad, wM, wN);
    mfma_step(As1, Bs1, acc, lm, quad, wM, wN);
    __syncthreads();
  }
#pragma unroll 1
  for (int w = 8; w < 14; ++w){           // fd: interleaved sin/cos pairs
    int k0 = w*64;
    int jb0 = (k0 + cA - 512) >> 1;       // 4 angles per half-window
    ushort8v o0, o1;
#pragma unroll
    for (int ii = 0; ii < 4; ++ii){
      int jj = jb0 + ii;
      int dim = jj >> 6; float kf = (float)(jj & 63);
      float fr = (dim == 0) ? f0x : ((dim == 1) ? f0y : f0z);
      float q = __builtin_amdgcn_fractf(fr * kf);
      o0[2*ii]   = f2bf(__builtin_amdgcn_sinf(q));
      o0[2*ii+1] = f2bf(__builtin_amdgcn_cosf(q));
    }
#pragma unroll
    for (int ii = 0; ii < 4; ++ii){
      int jj = jb0 + 16 + ii;
      int dim = jj >> 6; float kf = (float)(jj & 63);
      float fr = (dim == 0) ? f0x : ((dim == 1) ? f0y : f0z);
      float q = __builtin_amdgcn_fractf(fr * kf);
      o1[2*ii]   = f2bf(__builtin_amdgcn_sinf(q));
      o1[2*ii+1] = f2bf(__builtin_amdgcn_cosf(q));
    }
    *(ushort8v*)a0d = o0;
    *(ushort8v*)a1d = o1;
    gll16(W1T + btb0 + k0,      b0d0);
    gll16(W1T + btb1 + k0,      b0d1);
    gll16(W1T + btb0 + k0 + 32, b1d0);
    gll16(W1T + btb1 + k0 + 32, b1d1);
    __syncthreads();
    mfma_step(As0, Bs0, acc, lm, quad, wM, wN);
    mfma_step(As1, Bs1, acc, lm, quad, wM, wN);
    __syncthreads();
  }
  {                                       // half window k0=896: le + pad (As0/Bs0 only)
    ushort8v o0;
#pragma unroll
    for (int i = 0; i < 8; ++i){
      int c = cA + i;
      o0[i] = (c < 9) ? f2bf(ltl[g0*9 + c]) : (UST)0;
    }
    *(ushort8v*)a0d = o0;
    gll16(W1T + btb0 + 896, b0d0);
    gll16(W1T + btb1 + 896, b0d1);
    __syncthreads();
    mfma_step(As0, Bs0, acc, lm, quad, wM, wN);
  }
  // phase-1 epilogue: silu -> e1 tile (global scratch; this block's rows only)
  {
    int mbase = bM*128 + wM + quad*4;
    int nbase = wN + lm;
#pragma unroll
    for (int mi = 0; mi < 4; ++mi)
#pragma unroll
      for (int r = 0; r < 4; ++r){
        int m = mbase + mi*16 + r;
#pragma unroll
        for (int ni = 0; ni < 4; ++ni){
          int n = nbase + ni*16;
          float v = acc[mi][ni][r] + be1[n];
          e1[(size_t)m*256 + n] = f2bf(siluf(v));
        }
      }
  }
  __syncthreads();   // drains vmcnt(0): e1 tile visible; LDS buffers free

  // ---- phase 2: e2 = silu(e1 @ We2 + be2), K=256, A read back L2-hot ----
  floatx4 acc2[4][4] = {};
  size_t ab  = (size_t)(bM*128 + rA)*256 + cA;
  size_t bb0 = (size_t)rA*256 + cA;
  size_t bb1 = bb0 + (size_t)128*256;
#pragma unroll 1
  for (int k0 = 0; k0 < 256; k0 += 64){
    gll16(e1 + ab + k0,        a0d);
    gll16(e1 + ab + k0 + 32,   a1d);
    gll16(W2T + bb0 + k0,      b0d0);
    gll16(W2T + bb1 + k0,      b0d1);
    gll16(W2T + bb0 + k0 + 32, b1d0);
    gll16(W2T + bb1 + k0 + 32, b1d1);
    __syncthreads();
    mfma_step(As0, Bs0, acc2, lm, quad, wM, wN);
    mfma_step(As1, Bs1, acc2, lm, quad, wM, wN);
    __syncthreads();
  }
  // ---- phase 3: silu + transpose-store to EsT, segmented column sums ----
#pragma unroll
  for (int mi = 0; mi < 4; ++mi)
#pragma unroll
    for (int ni = 0; ni < 4; ++ni){
      int nl = wN + ni*16 + lm;
      int ml = wM + mi*16 + quad*4;
      ushort4v pk;
#pragma unroll
      for (int r = 0; r < 4; ++r)
        pk[r] = f2bf(siluf(acc2[mi][ni][r] + be2[nl]));
      *(ushort4v*)&EsT[nl*132 + ml] = pk;
    }
  __syncthreads();
  if (t < 256){
    int c = t;
    int cur = rn[0];
    float run = 0.0f;
#pragma unroll 1
    for (int r = 0; r < 128; r += 4){
      ushort4v v4 = *(const ushort4v*)&EsT[c*132 + r];
#pragma unroll
      for (int q2 = 0; q2 < 4; ++q2){
        int nd = rn[r + q2];
        if (nd != cur){ atomicAdd(&sums[(size_t)cur*256 + c], run); run = 0.0f; cur = nd; }
        run += bf2f(v4[q2]);
      }
    }
    atomicAdd(&sums[(size_t)cur*256 + c], run);
  }
}

// ---------------- node MLP1 with fused yA construction ----------------
// A row m: [h[m] (gll16) | sums[m]/deg (VALU-built)], K=512; rows >= N_NODES are zero.
__global__ __launch_bounds__(512)
void gemm_node1(const UST* __restrict__ h, const float* __restrict__ sums,
                const int* __restrict__ offs, const UST* __restrict__ B,
                const float* __restrict__ bias, UST* __restrict__ out){
  __shared__ __attribute__((aligned(16))) UST As0[128*32];
  __shared__ __attribute__((aligned(16))) UST As1[128*32];
  __shared__ __attribute__((aligned(16))) UST Bs0[256*32];
  __shared__ __attribute__((aligned(16))) UST Bs1[256*32];
  int t = threadIdx.x;
  int bM = blockIdx.x;
  int rA = t >> 2, cA = (t & 3) * 8;
  int row = bM*128 + rA;
  bool valid = row < N_NODES;
  float inv = 0.0f;
  if (valid){
    int deg = offs[row+1] - offs[row];
    inv = 1.0f / fmaxf((float)deg, 1.0f);
  }
  const UST* hrow = h + (size_t)row*256;
  const float* srow = sums + (size_t)row*256;
  size_t bb0 = (size_t)rA*512 + cA;
  size_t bb1 = bb0 + (size_t)128*512;
  int lane = t & 63, lm = lane & 15, quad = lane >> 4;
  int wave = t >> 6, wM = (wave >> 2)*64, wN = (wave & 3)*64;
  floatx4 acc[4][4] = {};
  UST* a0d = &As0[rA*32 + cA];
  UST* a1d = &As1[rA*32 + cA];
  UST* b0d0 = &Bs0[rA*32 + cA];
  UST* b0d1 = &Bs0[(128+rA)*32 + cA];
  UST* b1d0 = &Bs1[rA*32 + cA];
  UST* b1d1 = &Bs1[(128+rA)*32 + cA];
  const ushort8v z8 = {0,0,0,0,0,0,0,0};
#pragma unroll 1
  for (int w = 0; w < 8; ++w){
    int k0 = w*64;
    if (k0 < 256){                      // h half via async copy
      if (valid){
        gll16(hrow + k0 + cA,      a0d);
        gll16(hrow + k0 + 32 + cA, a1d);
      } else {
        *(ushort8v*)a0d = z8;
        *(ushort8v*)a1d = z8;
      }
    } else {                            // agg half built from sums/deg
      ushort8v o0 = z8, o1 = z8;
      if (valid){
        int q = k0 - 256 + cA;
        float4 s0 = *(const float4*)(srow + q);
        float4 s1 = *(const float4*)(srow + q + 4);
        o0[0]=f2bf(s0.x*inv); o0[1]=f2bf(s0.y*inv); o0[2]=f2bf(s0.z*inv); o0[3]=f2bf(s0.w*inv);
        o0[4]=f2bf(s1.x*inv); o0[5]=f2bf(s1.y*inv); o0[6]=f2bf(s1.z*inv); o0[7]=f2bf(s1.w*inv);
        float4 s2 = *(const float4*)(srow + q + 32);
        float4 s3 = *(const float4*)(srow + q + 36);
        o1[0]=f2bf(s2.x*inv); o1[1]=f2bf(s2.y*inv); o1[2]=f2bf(s2.z*inv); o1[3]=f2bf(s2.w*inv);
        o1[4]=f2bf(s3.x*inv); o1[5]=f2bf(s3.y*inv); o1[6]=f2bf(s3.z*inv); o1[7]=f2bf(s3.w*inv);
      }
      *(ushort8v*)a0d = o0;
      *(ushort8v*)a1d = o1;
    }
    gll16(B + bb0 + k0,      b0d0);
    gll16(B + bb1 + k0,      b0d1);
    gll16(B + bb0 + k0 + 32, b1d0);
    gll16(B + bb1 + k0 + 32, b1d1);
    __syncthreads();
    mfma_step(As0, Bs0, acc, lm, quad, wM, wN);
    mfma_step(As1, Bs1, acc, lm, quad, wM, wN);
    __syncthreads();
  }
  int mbase = bM*128 + wM + quad*4;
  int nbase = wN + lm;
#pragma unroll
  for (int mi = 0; mi < 4; ++mi)
#pragma unroll
    for (int r = 0; r < 4; ++r){
      int m = mbase + mi*16 + r;
#pragma unroll
      for (int ni = 0; ni < 4; ++ni){
        int n = nbase + ni*16;
        out[(size_t)m*256 + n] = f2bf(siluf(acc[mi][ni][r] + bias[n]));
      }
    }
}

// ---------------- node MLP2: K=256, silu + residual, fp32 out ----------------
__global__ __launch_bounds__(512)
void gemm_node2(const UST* __restrict__ A, const UST* __restrict__ B,
                const float* __restrict__ bias,
                float* __restrict__ out_f, const float* __restrict__ resid){
  __shared__ __attribute__((aligned(16))) UST As0[128*32];
  __shared__ __attribute__((aligned(16))) UST As1[128*32];
  __shared__ __attribute__((aligned(16))) UST Bs0[256*32];
  __shared__ __attribute__((aligned(16))) UST Bs1[256*32];
  int t = threadIdx.x;
  int bM = blockIdx.x;
  int rA = t >> 2, cA = (t & 3) * 8;
  size_t ab  = (size_t)(bM*128 + rA)*256 + cA;
  size_t bb0 = (size_t)rA*256 + cA;
  size_t bb1 = bb0 + (size_t)128*256;
  int lane = t & 63, lm = lane & 15, quad = lane >> 4;
  int wave = t >> 6, wM = (wave >> 2)*64, wN = (wave & 3)*64;
  floatx4 acc[4][4] = {};
  UST* a0d = &As0[rA*32 + cA];
  UST* a1d = &As1[rA*32 + cA];
  UST* b0d0 = &Bs0[rA*32 + cA];
  UST* b0d1 = &Bs0[(128+rA)*32 + cA];
  UST* b1d0 = &Bs1[rA*32 + cA];
  UST* b1d1 = &Bs1[(128+rA)*32 + cA];
#pragma unroll 1
  for (int k0 = 0; k0 < 256; k0 += 64){
    gll16(A + ab + k0,       a0d);
    gll16(A + ab + k0 + 32,  a1d);
    gll16(B + bb0 + k0,      b0d0);
    gll16(B + bb1 + k0,      b0d1);
    gll16(B + bb0 + k0 + 32, b1d0);
    gll16(B + bb1 + k0 + 32, b1d1);
    __syncthreads();
    mfma_step(As0, Bs0, acc, lm, quad, wM, wN);
    mfma_step(As1, Bs1, acc, lm, quad, wM, wN);
    __syncthreads();
  }
  int mbase = bM*128 + wM + quad*4;
  int nbase = wN + lm;
#pragma unroll
  for (int mi = 0; mi < 4; ++mi)
#pragma unroll
    for (int r = 0; r < 4; ++r){
      int m = mbase + mi*16 + r;
      if (m < N_NODES){
#pragma unroll
        for (int ni = 0; ni < 4; ++ni){
          int n = nbase + ni*16;
          float v = siluf(acc[mi][ni][r] + bias[n]);
          out_f[(size_t)m*256 + n] = resid[(size_t)m*256 + n] + v;
        }
      }
    }
}

extern "C" void kernel_launch(void* const* d_in, const int* in_sizes, int n_in,
                              void* d_out, int out_size, void* d_ws, size_t ws_size,
                              hipStream_t stream){
  (void)in_sizes; (void)n_in; (void)out_size; (void)ws_size;
  const float* node_features = (const float*)d_in[0];
  const float* lattices      = (const float*)d_in[1];
  const int*   edge_index    = (const int*)d_in[2];   // [2,E]: row0=src, row1=dst
  const int*   edge2graph    = (const int*)d_in[3];
  const float* frac_diff     = (const float*)d_in[4];
  const float* ln_gamma      = (const float*)d_in[6];
  const float* ln_beta       = (const float*)d_in[7];
  const float* We1 = (const float*)d_in[8];
  const float* be1 = (const float*)d_in[9];
  const float* We2 = (const float*)d_in[10];
  const float* be2 = (const float*)d_in[11];
  const float* Wn1 = (const float*)d_in[12];
  const float* bn1 = (const float*)d_in[13];
  const float* Wn2 = (const float*)d_in[14];
  const float* bn2 = (const float*)d_in[15];

  char* w = (char*)d_ws;
  size_t off_b = 0;
  auto carve = [&](size_t bytes) -> char* {
    char* p = w + off_b; off_b += (bytes + 1023) & ~(size_t)1023; return p;
  };
  UST*   W1T  = (UST*)carve((size_t)256*KE*2);
  UST*   W2T  = (UST*)carve((size_t)256*256*2);
  UST*   Wn1T = (UST*)carve((size_t)256*512*2);
  UST*   Wn2T = (UST*)carve((size_t)256*256*2);
  UST*   hbf  = (UST*)carve((size_t)N_NODES*256*2);
  float* ltl  = (float*)carve((size_t)9000*4);
  int*   cnti = (int*)carve((size_t)20480*4);          // padded for int4 scan
  int*   offs = (int*)carve((size_t)(N_NODES+1)*4);
  int*   head = (int*)carve((size_t)N_NODES*4);
  int*   eidx = (int*)carve((size_t)E_EDGES*4);
  int*   srcs = (int*)carve((size_t)E_EDGES*4);        // sorted src per CSR slot
  float* sums = (float*)carve((size_t)N_NODES*256*4);
  UST*   e1   = (UST*)carve((size_t)E_EDGES*256*2);    // in-kernel scratch (L2-hot readback)
  UST*   t1   = (UST*)carve((size_t)M_PAD*256*2);

  hipMemsetAsync(cnti, 0, (size_t)20480*4, stream);
  hipMemsetAsync(sums, 0, (size_t)N_NODES*256*4, stream);

  prep_w<<<928, 256, 0, stream>>>(We1, We2, Wn1, Wn2, W1T, W2T, Wn1T, Wn2T);
  ln_kernel<<<N_NODES/4, 256, 0, stream>>>(node_features, ln_gamma, ln_beta, hbf);
  ltl_kernel<<<36, 256, 0, stream>>>(lattices, ltl);

  cnt_kernel<<<E_EDGES/256, 256, 0, stream>>>(edge_index, cnti);
  scan_kernel<<<1, 256, 0, stream>>>(cnti, offs, head);
  fill_kernel<<<E_EDGES/256, 256, 0, stream>>>(edge_index, head, eidx, srcs);

  gemm_edge_fused<<<E_EDGES/128, 512, 0, stream>>>(
      hbf, edge_index, edge2graph, frac_diff, ltl, W1T, be1, eidx,
      W2T, be2, srcs, e1, sums);

  gemm_node1<<<M_PAD/128, 512, 0, stream>>>(hbf, sums, offs, Wn1T, bn1, t1);

  gemm_node2<<<M_PAD/128, 512, 0, stream>>>(
      t1, Wn2T, bn2, (float*)d_out, node_features);
}